// Round 4
// baseline (1592.319 us; speedup 1.0000x reference)
//
#include <hip/hip_runtime.h>
#include <hip/hip_bf16.h>

#define NN 50000
#define NE 600000
#define IND 16
#define EDD 8
#define HIDD 128
#define NH 4
#define CC 32
#define EMBD 64
#define FEATD 64

typedef __hip_bfloat16 bf16;

__device__ __forceinline__ float b2f(bf16 v) { return __bfloat162float(v); }

template <bool F32>
__device__ __forceinline__ float LD(const void* p, long long i) {
    if constexpr (F32) return ((const float*)p)[i];
    else return __bfloat162float(((const bf16*)p)[i]);
}

// ---- dtype detector (fp32 misread as bf16 shows ~2^-8 rate of exp==0xFF halfwords)
__global__ void k_zero(int* __restrict__ cnt) { *cnt = 0; }

__global__ void k_detect(const unsigned short* __restrict__ x, int nhalf, int* __restrict__ cnt) {
    __shared__ int c;
    if (threadIdx.x == 0) c = 0;
    __syncthreads();
    int i = blockIdx.x * blockDim.x + threadIdx.x;
    int hits = 0;
    for (; i < nhalf; i += gridDim.x * blockDim.x)
        if ((x[i] & 0x7F80u) == 0x7F80u) hits++;
    if (hits) atomicAdd(&c, hits);
    __syncthreads();
    if (threadIdx.x == 0 && c) atomicAdd(cnt, c);
}

__device__ __forceinline__ bool is_f32(const int* cnt) { return *cnt > 8; }

// ---- CSR build: counting sort of edges by dst ----
__global__ void k_zerodeg(int* __restrict__ deg) {
    int i = blockIdx.x * blockDim.x + threadIdx.x;
    if (i < NN) deg[i] = 0;
}
__global__ void k_hist(const int* __restrict__ ei, int* __restrict__ deg) {
    int e = blockIdx.x * blockDim.x + threadIdx.x;
    if (e < NE) atomicAdd(&deg[ei[NE + e]], 1);
}
// single-block exclusive scan of deg -> off (NN+1) and cur (working copy)
__global__ void k_scan(const int* __restrict__ deg, int* __restrict__ off, int* __restrict__ cur) {
    __shared__ int sums[256];
    int t = threadIdx.x;
    const int chunk = (NN + 255) / 256;  // 196
    int lo = t * chunk, hi = min(lo + chunk, NN);
    int s = 0;
    for (int i = lo; i < hi; i++) s += deg[i];
    sums[t] = s;
    __syncthreads();
    for (int o = 1; o < 256; o <<= 1) {
        int v = (t >= o) ? sums[t - o] : 0;
        __syncthreads();
        if (t >= o) sums[t] += v;
        __syncthreads();
    }
    int run = (t == 0) ? 0 : sums[t - 1];
    for (int i = lo; i < hi; i++) {
        off[i] = run; cur[i] = run;
        run += deg[i];
    }
    if (t == 255) off[NN] = run;  // == NE
}
// eslot[e] = dst-sorted slot for edge e ; esrc[slot] = src of that edge
__global__ void k_fill(const int* __restrict__ ei, int* __restrict__ cur,
                       int* __restrict__ eslot, int* __restrict__ esrc) {
    int e = blockIdx.x * blockDim.x + threadIdx.x;
    if (e >= NE) return;
    int slot = atomicAdd(&cur[ei[NE + e]], 1);
    eslot[e] = slot;
    esrc[slot] = ei[e];
}

// ---- z[n] = concat(relu(x[n] @ W_in + b_in), emb[node_idx[n]])
template <bool F32>
__device__ void build_z_impl(const void* x, const int* __restrict__ node_idx, const void* emb,
                             const void* W_in, const void* b_in, float* __restrict__ z) {
    int n = blockIdx.x, t = threadIdx.x;  // 128
    if (t < FEATD) {
        float acc = LD<F32>(b_in, t);
        #pragma unroll
        for (int k = 0; k < IND; k++)
            acc += LD<F32>(x, (long long)n * IND + k) * LD<F32>(W_in, k * FEATD + t);
        z[n * HIDD + t] = fmaxf(acc, 0.f);
    } else {
        int j = t - FEATD;
        z[n * HIDD + t] = LD<F32>(emb, (long long)node_idx[n] * EMBD + j);
    }
}
__global__ void k_build_z(const int* cnt, const void* x, const int* node_idx, const void* emb,
                          const void* W_in, const void* b_in, float* z) {
    if (is_f32(cnt)) build_z_impl<true>(x, node_idx, emb, W_in, b_in, z);
    else             build_z_impl<false>(x, node_idx, emb, W_in, b_in, z);
}

// ---- xl = z@Wl+bl ; xr = z@Wr+br, 4 nodes/block, bf16 outputs
template <bool F32>
__device__ void proj_impl(const float* __restrict__ z, const void* Wl, const void* bl,
                          const void* Wr, const void* br, bf16* __restrict__ xl,
                          bf16* __restrict__ xr) {
    __shared__ float zr[4][HIDD];
    int n0 = blockIdx.x * 4, t = threadIdx.x;  // 128
    #pragma unroll
    for (int j = 0; j < 4; j++) zr[j][t] = z[(n0 + j) * HIDD + t];
    __syncthreads();
    float al[4], ar[4];
    float blv = LD<F32>(bl, t), brv = LD<F32>(br, t);
    #pragma unroll
    for (int j = 0; j < 4; j++) { al[j] = blv; ar[j] = brv; }
    for (int k = 0; k < HIDD; k++) {
        float wl = LD<F32>(Wl, k * HIDD + t);
        float wr = LD<F32>(Wr, k * HIDD + t);
        #pragma unroll
        for (int j = 0; j < 4; j++) {
            al[j] += zr[j][k] * wl;
            ar[j] += zr[j][k] * wr;
        }
    }
    #pragma unroll
    for (int j = 0; j < 4; j++) {
        xl[(n0 + j) * HIDD + t] = __float2bfloat16(al[j]);
        xr[(n0 + j) * HIDD + t] = __float2bfloat16(ar[j]);
    }
}
__global__ void k_proj(const int* cnt, const float* z, const void* Wl, const void* bl,
                       const void* Wr, const void* br, bf16* xl, bf16* xr) {
    if (is_f32(cnt)) proj_impl<true>(z, Wl, bl, Wr, br, xl, xr);
    else             proj_impl<false>(z, Wl, bl, Wr, br, xl, xr);
}

// ---- edge phase A: per edge, logit -> exp, store to dst-sorted slot. NO atomics.
template <bool F32>
__device__ void edgeA_impl(const void* ea, const int* __restrict__ ei, const int* __restrict__ eslot,
                           const void* We, const void* be, const void* att,
                           const bf16* __restrict__ xl, const bf16* __restrict__ xr,
                           float* __restrict__ exs) {
    __shared__ float sWe[EDD * HIDD];
    __shared__ float sbt[2 * HIDD];  // be | att
    __shared__ float sea[2][EDD];
    int tid = threadIdx.x;  // 256 = 2 edges x 128 channels
    for (int i = tid; i < EDD * HIDD; i += 256) sWe[i] = LD<F32>(We, i);
    if (tid < HIDD) sbt[tid] = LD<F32>(be, tid);
    else            sbt[tid] = LD<F32>(att, tid - HIDD);
    int el = tid >> 7;
    int t = tid & 127;
    int e = blockIdx.x * 2 + el;  // grid = NE/2 exactly
    if (t < EDD) sea[el][t] = LD<F32>(ea, (long long)e * EDD + t);
    __syncthreads();
    int src = ei[e], dst = ei[NE + e];
    float ee = sbt[t];
    #pragma unroll
    for (int d = 0; d < EDD; d++) ee += sea[el][d] * sWe[d * HIDD + t];
    float s = b2f(xl[(long long)src * HIDD + t]) + b2f(xr[(long long)dst * HIDD + t]) + ee;
    s = (s >= 0.f) ? s : 0.2f * s;
    float ls = s * sbt[HIDD + t];
    #pragma unroll
    for (int m = 16; m; m >>= 1) ls += __shfl_xor(ls, m, 32);
    if ((t & 31) == 0) {
        int slot = eslot[e];
        exs[slot * NH + (t >> 5)] = __expf(ls);
    }
}
__global__ void k_edgeA(const int* cnt, const void* ea, const int* ei, const int* eslot,
                        const void* We, const void* be, const void* att,
                        const bf16* xl, const bf16* xr, float* exs) {
    if (is_f32(cnt)) edgeA_impl<true>(ea, ei, eslot, We, be, att, xl, xr, exs);
    else             edgeA_impl<false>(ea, ei, eslot, We, be, att, xl, xr, exs);
}

// ---- phase B: per-dst gather-aggregate + fused bias/relu/residual/LayerNorm
template <bool F32>
__device__ void agg_impl(const int* __restrict__ off, const int* __restrict__ esrc,
                         const float* __restrict__ exs, const bf16* __restrict__ xl,
                         const void* bo, float* __restrict__ z, const void* g, const void* beta) {
    int n = blockIdx.x, t = threadIdx.x;  // 128
    int h = t >> 5;
    int lo = off[n], hi = off[n + 1];
    float acc = 0.f, den = 0.f;
    for (int i = lo; i < hi; i++) {
        int src = esrc[i];                       // broadcast load
        float exv = exs[i * NH + h];
        acc += exv * b2f(xl[(long long)src * HIDD + t]);  // 256B coalesced gather
        den += exv;
    }
    float hv = (den > 0.f) ? acc / den : 0.f;
    hv = fmaxf(hv + LD<F32>(bo, t), 0.f);
    float v = z[n * HIDD + t] + hv;
    // LayerNorm over 128 channels
    int wave = t >> 6, lane = t & 63;
    __shared__ float part[2], part2[2];
    float s = v;
    #pragma unroll
    for (int o = 32; o; o >>= 1) s += __shfl_down(s, o);
    if (lane == 0) part[wave] = s;
    __syncthreads();
    float mu = (part[0] + part[1]) * (1.f / HIDD);
    float d = v - mu;
    float s2 = d * d;
    #pragma unroll
    for (int o = 32; o; o >>= 1) s2 += __shfl_down(s2, o);
    if (lane == 0) part2[wave] = s2;
    __syncthreads();
    float var = (part2[0] + part2[1]) * (1.f / HIDD);
    z[n * HIDD + t] = d * rsqrtf(var + 1e-5f) * LD<F32>(g, t) + LD<F32>(beta, t);
}
__global__ void k_agg(const int* cnt, const int* off, const int* esrc, const float* exs,
                      const bf16* xl, const void* bo, float* z, const void* g, const void* beta) {
    if (is_f32(cnt)) agg_impl<true>(off, esrc, exs, xl, bo, z, g, beta);
    else             agg_impl<false>(off, esrc, exs, xl, bo, z, g, beta);
}

// ---- out[n] = z[n] @ W_out + b_out
template <bool F32>
__device__ void head_impl(const float* __restrict__ z, const void* Wo, const void* bo, void* out) {
    int n = blockIdx.x;
    int lane = threadIdx.x;  // 64
    float acc = z[n * HIDD + lane] * LD<F32>(Wo, lane) +
                z[n * HIDD + 64 + lane] * LD<F32>(Wo, 64 + lane);
    #pragma unroll
    for (int o = 32; o; o >>= 1) acc += __shfl_down(acc, o);
    if (lane == 0) {
        float r = acc + LD<F32>(bo, 0);
        if constexpr (F32) ((float*)out)[n] = r;
        else               ((bf16*)out)[n] = __float2bfloat16(r);
    }
}
__global__ void k_head(const int* cnt, const float* z, const void* Wo, const void* bo, void* out) {
    if (is_f32(cnt)) head_impl<true>(z, Wo, bo, out);
    else             head_impl<false>(z, Wo, bo, out);
}

extern "C" void kernel_launch(void* const* d_in, const int* in_sizes, int n_in,
                              void* d_out, int out_size, void* d_ws, size_t ws_size,
                              hipStream_t stream) {
    const void* x        = d_in[0];
    const int*  node_idx = (const int*)d_in[1];
    const int*  ei       = (const int*)d_in[2];
    const void* ea       = d_in[3];
    const void* emb      = d_in[4];
    const void* W_in     = d_in[5];
    const void* b_in     = d_in[6];
    const void* Wl1 = d_in[7];  const void* bl1 = d_in[8];
    const void* Wr1 = d_in[9];  const void* br1 = d_in[10];
    const void* We1 = d_in[11]; const void* be1 = d_in[12];
    const void* att1 = d_in[13]; const void* bo1 = d_in[14];
    const void* Wl2 = d_in[15]; const void* bl2 = d_in[16];
    const void* Wr2 = d_in[17]; const void* br2 = d_in[18];
    const void* We2 = d_in[19]; const void* be2 = d_in[20];
    const void* att2 = d_in[21]; const void* bo2 = d_in[22];
    const void* g1 = d_in[23]; const void* beta1 = d_in[24];
    const void* g2 = d_in[25]; const void* beta2 = d_in[26];
    const void* W_out = d_in[27]; const void* b_out = d_in[28];

    // workspace: cnt | z f32 | exs f32 | off/cur/eslot/esrc int | xl/xr bf16   (~66 MB)
    int* cnt    = (int*)d_ws;
    float* z    = (float*)d_ws + 64;          // NN*HIDD
    float* exs  = z + NN * HIDD;              // NE*NH
    int* off    = (int*)(exs + NE * NH);      // NN+1
    int* cur    = off + NN + 1;               // NN
    int* eslot  = cur + NN;                   // NE
    int* esrc   = eslot + NE;                 // NE
    bf16* xl    = (bf16*)(esrc + NE);         // NN*HIDD
    bf16* xr    = xl + NN * HIDD;             // NN*HIDD

    int nhalf = in_sizes[0] < 65536 ? in_sizes[0] : 65536;
    k_zero<<<1, 1, 0, stream>>>(cnt);
    k_detect<<<64, 256, 0, stream>>>((const unsigned short*)x, nhalf, cnt);
    k_build_z<<<NN, 128, 0, stream>>>(cnt, x, node_idx, emb, W_in, b_in, z);

    // CSR by dst (shared by both layers); cur doubles as deg buffer first
    k_zerodeg<<<(NN + 255) / 256, 256, 0, stream>>>(cur);
    k_hist<<<(NE + 255) / 256, 256, 0, stream>>>(ei, cur);
    k_scan<<<1, 256, 0, stream>>>(cur, off, cur);  // reads deg=cur, writes off + cur
    k_fill<<<(NE + 255) / 256, 256, 0, stream>>>(ei, cur, eslot, esrc);

    // ---- layer 1 ----
    k_proj<<<NN / 4, 128, 0, stream>>>(cnt, z, Wl1, bl1, Wr1, br1, xl, xr);
    k_edgeA<<<NE / 2, 256, 0, stream>>>(cnt, ea, ei, eslot, We1, be1, att1, xl, xr, exs);
    k_agg<<<NN, 128, 0, stream>>>(cnt, off, esrc, exs, xl, bo1, z, g1, beta1);

    // ---- layer 2 ----
    k_proj<<<NN / 4, 128, 0, stream>>>(cnt, z, Wl2, bl2, Wr2, br2, xl, xr);
    k_edgeA<<<NE / 2, 256, 0, stream>>>(cnt, ea, ei, eslot, We2, be2, att2, xl, xr, exs);
    k_agg<<<NN, 128, 0, stream>>>(cnt, off, esrc, exs, xl, bo2, z, g2, beta2);

    k_head<<<NN, 64, 0, stream>>>(cnt, z, W_out, b_out, d_out);
}

// Round 5
// 851.629 us; speedup vs baseline: 1.8697x; 1.8697x over previous
//
#include <hip/hip_runtime.h>
#include <hip/hip_bf16.h>

#define NN 50000
#define NE 600000
#define IND 16
#define EDD 8
#define HIDD 128
#define NH 4
#define CC 32
#define EMBD 64
#define FEATD 64

typedef __hip_bfloat16 bf16;

__device__ __forceinline__ float b2f(bf16 v) { return __bfloat162float(v); }

template <bool F32>
__device__ __forceinline__ float LD(const void* p, long long i) {
    if constexpr (F32) return ((const float*)p)[i];
    else return __bfloat162float(((const bf16*)p)[i]);
}

// ---- dtype detector (fp32 misread as bf16 shows ~2^-8 rate of exp==0xFF halfwords)
__global__ void k_zero(int* __restrict__ cnt) { *cnt = 0; }

__global__ void k_detect(const unsigned short* __restrict__ x, int nhalf, int* __restrict__ cnt) {
    __shared__ int c;
    if (threadIdx.x == 0) c = 0;
    __syncthreads();
    int i = blockIdx.x * blockDim.x + threadIdx.x;
    int hits = 0;
    for (; i < nhalf; i += gridDim.x * blockDim.x)
        if ((x[i] & 0x7F80u) == 0x7F80u) hits++;
    if (hits) atomicAdd(&c, hits);
    __syncthreads();
    if (threadIdx.x == 0 && c) atomicAdd(cnt, c);
}

__device__ __forceinline__ bool is_f32(const int* cnt) { return *cnt > 8; }

// ---- CSR build: counting sort of edges by dst ----
__global__ void k_zerodeg(int* __restrict__ deg) {
    int i = blockIdx.x * blockDim.x + threadIdx.x;
    if (i < NN) deg[i] = 0;
}
__global__ void k_hist(const int* __restrict__ ei, int* __restrict__ deg) {
    int e = blockIdx.x * blockDim.x + threadIdx.x;
    if (e < NE) atomicAdd(&deg[ei[NE + e]], 1);
}
__global__ void k_scan(const int* __restrict__ deg, int* __restrict__ off, int* __restrict__ cur) {
    __shared__ int sums[256];
    int t = threadIdx.x;
    const int chunk = (NN + 255) / 256;
    int lo = t * chunk, hi = min(lo + chunk, NN);
    int s = 0;
    for (int i = lo; i < hi; i++) s += deg[i];
    sums[t] = s;
    __syncthreads();
    for (int o = 1; o < 256; o <<= 1) {
        int v = (t >= o) ? sums[t - o] : 0;
        __syncthreads();
        if (t >= o) sums[t] += v;
        __syncthreads();
    }
    int run = (t == 0) ? 0 : sums[t - 1];
    for (int i = lo; i < hi; i++) {
        off[i] = run; cur[i] = run;
        run += deg[i];
    }
    if (t == 255) off[NN] = run;
}
// esrc[slot] = src of edge ; eid[slot] = original edge index (for edge_attr)
__global__ void k_fill(const int* __restrict__ ei, int* __restrict__ cur,
                       int* __restrict__ esrc, int* __restrict__ eid) {
    int e = blockIdx.x * blockDim.x + threadIdx.x;
    if (e >= NE) return;
    int slot = atomicAdd(&cur[ei[NE + e]], 1);
    esrc[slot] = ei[e];
    eid[slot] = e;
}

// ---- z[n] = concat(relu(x[n] @ W_in + b_in), emb[node_idx[n]])
template <bool F32>
__device__ void build_z_impl(const void* x, const int* __restrict__ node_idx, const void* emb,
                             const void* W_in, const void* b_in, float* __restrict__ z) {
    int n = blockIdx.x, t = threadIdx.x;  // 128
    if (t < FEATD) {
        float acc = LD<F32>(b_in, t);
        #pragma unroll
        for (int k = 0; k < IND; k++)
            acc += LD<F32>(x, (long long)n * IND + k) * LD<F32>(W_in, k * FEATD + t);
        z[n * HIDD + t] = fmaxf(acc, 0.f);
    } else {
        int j = t - FEATD;
        z[n * HIDD + t] = LD<F32>(emb, (long long)node_idx[n] * EMBD + j);
    }
}
__global__ void k_build_z(const int* cnt, const void* x, const int* node_idx, const void* emb,
                          const void* W_in, const void* b_in, float* z) {
    if (is_f32(cnt)) build_z_impl<true>(x, node_idx, emb, W_in, b_in, z);
    else             build_z_impl<false>(x, node_idx, emb, W_in, b_in, z);
}

// ---- xl = z@Wl+bl ; xr = z@Wr+br, 4 nodes/block, bf16 outputs
template <bool F32>
__device__ void proj_impl(const float* __restrict__ z, const void* Wl, const void* bl,
                          const void* Wr, const void* br, bf16* __restrict__ xl,
                          bf16* __restrict__ xr) {
    __shared__ float zr[4][HIDD];
    int n0 = blockIdx.x * 4, t = threadIdx.x;  // 128
    #pragma unroll
    for (int j = 0; j < 4; j++) zr[j][t] = z[(n0 + j) * HIDD + t];
    __syncthreads();
    float al[4], ar[4];
    float blv = LD<F32>(bl, t), brv = LD<F32>(br, t);
    #pragma unroll
    for (int j = 0; j < 4; j++) { al[j] = blv; ar[j] = brv; }
    for (int k = 0; k < HIDD; k++) {
        float wl = LD<F32>(Wl, k * HIDD + t);
        float wr = LD<F32>(Wr, k * HIDD + t);
        #pragma unroll
        for (int j = 0; j < 4; j++) {
            al[j] += zr[j][k] * wl;
            ar[j] += zr[j][k] * wr;
        }
    }
    #pragma unroll
    for (int j = 0; j < 4; j++) {
        xl[(n0 + j) * HIDD + t] = __float2bfloat16(al[j]);
        xr[(n0 + j) * HIDD + t] = __float2bfloat16(ar[j]);
    }
}
__global__ void k_proj(const int* cnt, const float* z, const void* Wl, const void* bl,
                       const void* Wr, const void* br, bf16* xl, bf16* xr) {
    if (is_f32(cnt)) proj_impl<true>(z, Wl, bl, Wr, br, xl, xr);
    else             proj_impl<false>(z, Wl, bl, Wr, br, xl, xr);
}

// ---- fused GAT layer: per-dst block computes logits, softmax, aggregation,
//      bias/relu/residual/LayerNorm. No LDS except LN partials; We column in regs.
template <bool F32>
__device__ void gat_impl(const int* __restrict__ off, const int* __restrict__ esrc,
                         const int* __restrict__ eid, const void* ea,
                         const void* We, const void* be, const void* att,
                         const bf16* __restrict__ xl, const bf16* __restrict__ xr,
                         const void* bo, float* __restrict__ z,
                         const void* g, const void* beta) {
    int n = blockIdx.x, t = threadIdx.x;  // 128 threads = channels
    // per-thread constants: column t of We, plus be/att
    float wv[EDD];
    #pragma unroll
    for (int d = 0; d < EDD; d++) wv[d] = LD<F32>(We, d * HIDD + t);
    float be_t = LD<F32>(be, t);
    float att_t = LD<F32>(att, t);
    float xrv = b2f(xr[(long long)n * HIDD + t]);
    int lo = off[n], hi = off[n + 1];
    float acc = 0.f, den = 0.f;
    for (int i = lo; i < hi; i++) {
        int src = esrc[i];   // broadcast
        int e   = eid[i];    // broadcast
        float ee = be_t;
        #pragma unroll
        for (int d = 0; d < EDD; d++)
            ee += LD<F32>(ea, (long long)e * EDD + d) * wv[d];  // broadcast loads
        float xlv = b2f(xl[(long long)src * HIDD + t]);         // 256B coalesced gather
        float s = xlv + xrv + ee;
        s = (s >= 0.f) ? s : 0.2f * s;
        float ls = s * att_t;
        #pragma unroll
        for (int m = 16; m; m >>= 1) ls += __shfl_xor(ls, m, 32);  // per-head reduce
        float ex = __expf(ls);   // all 32 lanes of the head group hold the full sum
        acc += ex * xlv;
        den += ex;
    }
    float hv = (den > 0.f) ? acc / den : 0.f;
    hv = fmaxf(hv + LD<F32>(bo, t), 0.f);
    float v = z[(long long)n * HIDD + t] + hv;
    // LayerNorm over 128 channels
    int wave = t >> 6, lane = t & 63;
    __shared__ float part[2], part2[2];
    float s = v;
    #pragma unroll
    for (int o = 32; o; o >>= 1) s += __shfl_down(s, o);
    if (lane == 0) part[wave] = s;
    __syncthreads();
    float mu = (part[0] + part[1]) * (1.f / HIDD);
    float d = v - mu;
    float s2 = d * d;
    #pragma unroll
    for (int o = 32; o; o >>= 1) s2 += __shfl_down(s2, o);
    if (lane == 0) part2[wave] = s2;
    __syncthreads();
    float var = (part2[0] + part2[1]) * (1.f / HIDD);
    z[(long long)n * HIDD + t] = d * rsqrtf(var + 1e-5f) * LD<F32>(g, t) + LD<F32>(beta, t);
}
__global__ void k_gat(const int* cnt, const int* off, const int* esrc, const int* eid,
                      const void* ea, const void* We, const void* be, const void* att,
                      const bf16* xl, const bf16* xr, const void* bo, float* z,
                      const void* g, const void* beta) {
    if (is_f32(cnt)) gat_impl<true>(off, esrc, eid, ea, We, be, att, xl, xr, bo, z, g, beta);
    else             gat_impl<false>(off, esrc, eid, ea, We, be, att, xl, xr, bo, z, g, beta);
}

// ---- out[n] = z[n] @ W_out + b_out
template <bool F32>
__device__ void head_impl(const float* __restrict__ z, const void* Wo, const void* bo, void* out) {
    int n = blockIdx.x;
    int lane = threadIdx.x;  // 64
    float acc = z[n * HIDD + lane] * LD<F32>(Wo, lane) +
                z[n * HIDD + 64 + lane] * LD<F32>(Wo, 64 + lane);
    #pragma unroll
    for (int o = 32; o; o >>= 1) acc += __shfl_down(acc, o);
    if (lane == 0) {
        float r = acc + LD<F32>(bo, 0);
        if constexpr (F32) ((float*)out)[n] = r;
        else               ((bf16*)out)[n] = __float2bfloat16(r);
    }
}
__global__ void k_head(const int* cnt, const float* z, const void* Wo, const void* bo, void* out) {
    if (is_f32(cnt)) head_impl<true>(z, Wo, bo, out);
    else             head_impl<false>(z, Wo, bo, out);
}

extern "C" void kernel_launch(void* const* d_in, const int* in_sizes, int n_in,
                              void* d_out, int out_size, void* d_ws, size_t ws_size,
                              hipStream_t stream) {
    const void* x        = d_in[0];
    const int*  node_idx = (const int*)d_in[1];
    const int*  ei       = (const int*)d_in[2];
    const void* ea       = d_in[3];
    const void* emb      = d_in[4];
    const void* W_in     = d_in[5];
    const void* b_in     = d_in[6];
    const void* Wl1 = d_in[7];  const void* bl1 = d_in[8];
    const void* Wr1 = d_in[9];  const void* br1 = d_in[10];
    const void* We1 = d_in[11]; const void* be1 = d_in[12];
    const void* att1 = d_in[13]; const void* bo1 = d_in[14];
    const void* Wl2 = d_in[15]; const void* bl2 = d_in[16];
    const void* Wr2 = d_in[17]; const void* br2 = d_in[18];
    const void* We2 = d_in[19]; const void* be2 = d_in[20];
    const void* att2 = d_in[21]; const void* bo2 = d_in[22];
    const void* g1 = d_in[23]; const void* beta1 = d_in[24];
    const void* g2 = d_in[25]; const void* beta2 = d_in[26];
    const void* W_out = d_in[27]; const void* b_out = d_in[28];

    // workspace: cnt | z f32 | off | cur | esrc | eid | xl bf16 | xr bf16  (~56 MB)
    int* cnt    = (int*)d_ws;
    float* z    = (float*)d_ws + 64;          // NN*HIDD
    int* off    = (int*)(z + NN * HIDD);      // NN+1
    int* cur    = off + NN + 1;               // NN
    int* esrc   = cur + NN;                   // NE
    int* eid    = esrc + NE;                  // NE
    bf16* xl    = (bf16*)(eid + NE);          // NN*HIDD
    bf16* xr    = xl + NN * HIDD;             // NN*HIDD

    int nhalf = in_sizes[0] < 65536 ? in_sizes[0] : 65536;
    k_zero<<<1, 1, 0, stream>>>(cnt);
    k_detect<<<64, 256, 0, stream>>>((const unsigned short*)x, nhalf, cnt);
    k_build_z<<<NN, 128, 0, stream>>>(cnt, x, node_idx, emb, W_in, b_in, z);

    // CSR by dst (shared by both layers); cur doubles as deg buffer first
    k_zerodeg<<<(NN + 255) / 256, 256, 0, stream>>>(cur);
    k_hist<<<(NE + 255) / 256, 256, 0, stream>>>(ei, cur);
    k_scan<<<1, 256, 0, stream>>>(cur, off, cur);
    k_fill<<<(NE + 255) / 256, 256, 0, stream>>>(ei, cur, esrc, eid);

    // ---- layer 1 ----
    k_proj<<<NN / 4, 128, 0, stream>>>(cnt, z, Wl1, bl1, Wr1, br1, xl, xr);
    k_gat<<<NN, 128, 0, stream>>>(cnt, off, esrc, eid, ea, We1, be1, att1, xl, xr, bo1, z, g1, beta1);

    // ---- layer 2 ----
    k_proj<<<NN / 4, 128, 0, stream>>>(cnt, z, Wl2, bl2, Wr2, br2, xl, xr);
    k_gat<<<NN, 128, 0, stream>>>(cnt, off, esrc, eid, ea, We2, be2, att2, xl, xr, bo2, z, g2, beta2);

    k_head<<<NN, 64, 0, stream>>>(cnt, z, W_out, b_out, d_out);
}

// Round 6
// 760.165 us; speedup vs baseline: 2.0947x; 1.1203x over previous
//
#include <hip/hip_runtime.h>
#include <hip/hip_bf16.h>

#define NN 50000
#define NE 600000
#define IND 16
#define EDD 8
#define HIDD 128
#define NH 4
#define CC 32
#define EMBD 64
#define FEATD 64

typedef __hip_bfloat16 bf16;

__device__ __forceinline__ float b2f(bf16 v) { return __bfloat162float(v); }

template <bool F32>
__device__ __forceinline__ float LD(const void* p, long long i) {
    if constexpr (F32) return ((const float*)p)[i];
    else return __bfloat162float(((const bf16*)p)[i]);
}

// ---- dtype detector (fp32 misread as bf16 shows ~2^-8 rate of exp==0xFF halfwords)
__global__ void k_zero(int* __restrict__ cnt) { *cnt = 0; }

__global__ void k_detect(const unsigned short* __restrict__ x, int nhalf, int* __restrict__ cnt) {
    __shared__ int c;
    if (threadIdx.x == 0) c = 0;
    __syncthreads();
    int i = blockIdx.x * blockDim.x + threadIdx.x;
    int hits = 0;
    for (; i < nhalf; i += gridDim.x * blockDim.x)
        if ((x[i] & 0x7F80u) == 0x7F80u) hits++;
    if (hits) atomicAdd(&c, hits);
    __syncthreads();
    if (threadIdx.x == 0 && c) atomicAdd(cnt, c);
}

__device__ __forceinline__ bool is_f32(const int* cnt) { return *cnt > 8; }

// ---- CSR build: counting sort of edges by dst ----
__global__ void k_zerodeg(int* __restrict__ deg) {
    int i = blockIdx.x * blockDim.x + threadIdx.x;
    if (i < NN) deg[i] = 0;
}
__global__ void k_hist(const int* __restrict__ ei, int* __restrict__ deg) {
    int e = blockIdx.x * blockDim.x + threadIdx.x;
    if (e < NE) atomicAdd(&deg[ei[NE + e]], 1);
}
__global__ void k_scan(const int* __restrict__ deg, int* __restrict__ off, int* __restrict__ cur) {
    __shared__ int sums[256];
    int t = threadIdx.x;
    const int chunk = (NN + 255) / 256;
    int lo = t * chunk, hi = min(lo + chunk, NN);
    int s = 0;
    for (int i = lo; i < hi; i++) s += deg[i];
    sums[t] = s;
    __syncthreads();
    for (int o = 1; o < 256; o <<= 1) {
        int v = (t >= o) ? sums[t - o] : 0;
        __syncthreads();
        if (t >= o) sums[t] += v;
        __syncthreads();
    }
    int run = (t == 0) ? 0 : sums[t - 1];
    for (int i = lo; i < hi; i++) {
        off[i] = run; cur[i] = run;
        run += deg[i];
    }
    if (t == 255) off[NN] = run;
}
// esrc[slot] = src ; ea_s[slot][8] = edge_attr (fp32, CSR-sorted, shared by both layers)
template <bool F32>
__device__ void fill_impl(const int* __restrict__ ei, int* __restrict__ cur,
                          int* __restrict__ esrc, float* __restrict__ ea_s, const void* ea) {
    int e = blockIdx.x * blockDim.x + threadIdx.x;
    if (e >= NE) return;
    int slot = atomicAdd(&cur[ei[NE + e]], 1);
    esrc[slot] = ei[e];
    float4 v0, v1;
    v0.x = LD<F32>(ea, (long long)e * EDD + 0); v0.y = LD<F32>(ea, (long long)e * EDD + 1);
    v0.z = LD<F32>(ea, (long long)e * EDD + 2); v0.w = LD<F32>(ea, (long long)e * EDD + 3);
    v1.x = LD<F32>(ea, (long long)e * EDD + 4); v1.y = LD<F32>(ea, (long long)e * EDD + 5);
    v1.z = LD<F32>(ea, (long long)e * EDD + 6); v1.w = LD<F32>(ea, (long long)e * EDD + 7);
    float4* dstp = (float4*)(ea_s + (long long)slot * EDD);
    dstp[0] = v0; dstp[1] = v1;
}
__global__ void k_fill(const int* cnt, const int* ei, int* cur, int* esrc, float* ea_s,
                       const void* ea) {
    if (is_f32(cnt)) fill_impl<true>(ei, cur, esrc, ea_s, ea);
    else             fill_impl<false>(ei, cur, esrc, ea_s, ea);
}

// ---- z[n] = concat(relu(x[n] @ W_in + b_in), emb[node_idx[n]])
template <bool F32>
__device__ void build_z_impl(const void* x, const int* __restrict__ node_idx, const void* emb,
                             const void* W_in, const void* b_in, float* __restrict__ z) {
    int n = blockIdx.x, t = threadIdx.x;  // 128
    if (t < FEATD) {
        float acc = LD<F32>(b_in, t);
        #pragma unroll
        for (int k = 0; k < IND; k++)
            acc += LD<F32>(x, (long long)n * IND + k) * LD<F32>(W_in, k * FEATD + t);
        z[n * HIDD + t] = fmaxf(acc, 0.f);
    } else {
        int j = t - FEATD;
        z[n * HIDD + t] = LD<F32>(emb, (long long)node_idx[n] * EMBD + j);
    }
}
__global__ void k_build_z(const int* cnt, const void* x, const int* node_idx, const void* emb,
                          const void* W_in, const void* b_in, float* z) {
    if (is_f32(cnt)) build_z_impl<true>(x, node_idx, emb, W_in, b_in, z);
    else             build_z_impl<false>(x, node_idx, emb, W_in, b_in, z);
}

// ---- xl = z@Wl+bl ; xr = z@Wr+br, 8 nodes/block, bf16 outputs
#define PROJ_J 8
template <bool F32>
__device__ void proj_impl(const float* __restrict__ z, const void* Wl, const void* bl,
                          const void* Wr, const void* br, bf16* __restrict__ xl,
                          bf16* __restrict__ xr) {
    __shared__ float zr[PROJ_J][HIDD];
    int n0 = blockIdx.x * PROJ_J, t = threadIdx.x;  // 128
    #pragma unroll
    for (int j = 0; j < PROJ_J; j++) zr[j][t] = z[(n0 + j) * HIDD + t];
    __syncthreads();
    float al[PROJ_J], ar[PROJ_J];
    float blv = LD<F32>(bl, t), brv = LD<F32>(br, t);
    #pragma unroll
    for (int j = 0; j < PROJ_J; j++) { al[j] = blv; ar[j] = brv; }
    for (int k = 0; k < HIDD; k++) {
        float wl = LD<F32>(Wl, k * HIDD + t);
        float wr = LD<F32>(Wr, k * HIDD + t);
        #pragma unroll
        for (int j = 0; j < PROJ_J; j++) {
            al[j] += zr[j][k] * wl;
            ar[j] += zr[j][k] * wr;
        }
    }
    #pragma unroll
    for (int j = 0; j < PROJ_J; j++) {
        xl[(n0 + j) * HIDD + t] = __float2bfloat16(al[j]);
        xr[(n0 + j) * HIDD + t] = __float2bfloat16(ar[j]);
    }
}
__global__ void k_proj(const int* cnt, const float* z, const void* Wl, const void* bl,
                       const void* Wr, const void* br, bf16* xl, bf16* xr) {
    if (is_f32(cnt)) proj_impl<true>(z, Wl, bl, Wr, br, xl, xr);
    else             proj_impl<false>(z, Wl, bl, Wr, br, xl, xr);
}

// ---- fused GAT layer: per-dst block; CSR-sorted streaming ea_s; fused LN epilogue
template <bool F32>
__device__ void gat_impl(const int* __restrict__ off, const int* __restrict__ esrc,
                         const float* __restrict__ ea_s,
                         const void* We, const void* be, const void* att,
                         const bf16* __restrict__ xl, const bf16* __restrict__ xr,
                         const void* bo, float* __restrict__ z,
                         const void* g, const void* beta) {
    int n = blockIdx.x, t = threadIdx.x;  // 128 threads = channels
    float wv[EDD];
    #pragma unroll
    for (int d = 0; d < EDD; d++) wv[d] = LD<F32>(We, d * HIDD + t);
    float be_t = LD<F32>(be, t);
    float att_t = LD<F32>(att, t);
    float xrv = b2f(xr[(long long)n * HIDD + t]);
    int lo = off[n], hi = off[n + 1];
    float acc = 0.f, den = 0.f;
    #pragma unroll 2
    for (int i = lo; i < hi; i++) {
        int src = esrc[i];  // broadcast, sequential address
        const float4* pe = (const float4*)(ea_s + (long long)i * EDD);
        float4 e0 = pe[0], e1 = pe[1];  // broadcast, sequential
        float ee = be_t;
        ee += e0.x * wv[0] + e0.y * wv[1] + e0.z * wv[2] + e0.w * wv[3];
        ee += e1.x * wv[4] + e1.y * wv[5] + e1.z * wv[6] + e1.w * wv[7];
        float xlv = b2f(xl[(long long)src * HIDD + t]);  // 256B coalesced gather
        float s = xlv + xrv + ee;
        s = (s >= 0.f) ? s : 0.2f * s;
        float ls = s * att_t;
        #pragma unroll
        for (int m = 16; m; m >>= 1) ls += __shfl_xor(ls, m, 32);  // per-head reduce
        float ex = __expf(ls);
        acc += ex * xlv;
        den += ex;
    }
    float hv = (den > 0.f) ? acc / den : 0.f;
    hv = fmaxf(hv + LD<F32>(bo, t), 0.f);
    float v = z[(long long)n * HIDD + t] + hv;
    // LayerNorm over 128 channels
    int wave = t >> 6, lane = t & 63;
    __shared__ float part[2], part2[2];
    float s = v;
    #pragma unroll
    for (int o = 32; o; o >>= 1) s += __shfl_down(s, o);
    if (lane == 0) part[wave] = s;
    __syncthreads();
    float mu = (part[0] + part[1]) * (1.f / HIDD);
    float d = v - mu;
    float s2 = d * d;
    #pragma unroll
    for (int o = 32; o; o >>= 1) s2 += __shfl_down(s2, o);
    if (lane == 0) part2[wave] = s2;
    __syncthreads();
    float var = (part2[0] + part2[1]) * (1.f / HIDD);
    z[(long long)n * HIDD + t] = d * rsqrtf(var + 1e-5f) * LD<F32>(g, t) + LD<F32>(beta, t);
}
__global__ void k_gat(const int* cnt, const int* off, const int* esrc, const float* ea_s,
                      const void* We, const void* be, const void* att,
                      const bf16* xl, const bf16* xr, const void* bo, float* z,
                      const void* g, const void* beta) {
    if (is_f32(cnt)) gat_impl<true>(off, esrc, ea_s, We, be, att, xl, xr, bo, z, g, beta);
    else             gat_impl<false>(off, esrc, ea_s, We, be, att, xl, xr, bo, z, g, beta);
}

// ---- out[n] = z[n] @ W_out + b_out
template <bool F32>
__device__ void head_impl(const float* __restrict__ z, const void* Wo, const void* bo, void* out) {
    int n = blockIdx.x;
    int lane = threadIdx.x;  // 64
    float acc = z[n * HIDD + lane] * LD<F32>(Wo, lane) +
                z[n * HIDD + 64 + lane] * LD<F32>(Wo, 64 + lane);
    #pragma unroll
    for (int o = 32; o; o >>= 1) acc += __shfl_down(acc, o);
    if (lane == 0) {
        float r = acc + LD<F32>(bo, 0);
        if constexpr (F32) ((float*)out)[n] = r;
        else               ((bf16*)out)[n] = __float2bfloat16(r);
    }
}
__global__ void k_head(const int* cnt, const float* z, const void* Wo, const void* bo, void* out) {
    if (is_f32(cnt)) head_impl<true>(z, Wo, bo, out);
    else             head_impl<false>(z, Wo, bo, out);
}

extern "C" void kernel_launch(void* const* d_in, const int* in_sizes, int n_in,
                              void* d_out, int out_size, void* d_ws, size_t ws_size,
                              hipStream_t stream) {
    const void* x        = d_in[0];
    const int*  node_idx = (const int*)d_in[1];
    const int*  ei       = (const int*)d_in[2];
    const void* ea       = d_in[3];
    const void* emb      = d_in[4];
    const void* W_in     = d_in[5];
    const void* b_in     = d_in[6];
    const void* Wl1 = d_in[7];  const void* bl1 = d_in[8];
    const void* Wr1 = d_in[9];  const void* br1 = d_in[10];
    const void* We1 = d_in[11]; const void* be1 = d_in[12];
    const void* att1 = d_in[13]; const void* bo1 = d_in[14];
    const void* Wl2 = d_in[15]; const void* bl2 = d_in[16];
    const void* Wr2 = d_in[17]; const void* br2 = d_in[18];
    const void* We2 = d_in[19]; const void* be2 = d_in[20];
    const void* att2 = d_in[21]; const void* bo2 = d_in[22];
    const void* g1 = d_in[23]; const void* beta1 = d_in[24];
    const void* g2 = d_in[25]; const void* beta2 = d_in[26];
    const void* W_out = d_in[27]; const void* b_out = d_in[28];

    // workspace (~74 MB): cnt | z f32 | ea_s f32[NE*8] | off | cur | esrc | xl bf16 | xr bf16
    int* cnt    = (int*)d_ws;
    float* z    = (float*)d_ws + 64;          // NN*HIDD f32
    float* ea_s = z + NN * HIDD;              // NE*EDD f32 (16B-aligned)
    int* off    = (int*)(ea_s + (long long)NE * EDD);  // NN+1
    int* cur    = off + NN + 1;               // NN
    int* esrc   = cur + NN;                   // NE
    bf16* xl    = (bf16*)(esrc + NE);         // NN*HIDD
    bf16* xr    = xl + NN * HIDD;             // NN*HIDD

    int nhalf = in_sizes[0] < 65536 ? in_sizes[0] : 65536;
    k_zero<<<1, 1, 0, stream>>>(cnt);
    k_detect<<<64, 256, 0, stream>>>((const unsigned short*)x, nhalf, cnt);
    k_build_z<<<NN, 128, 0, stream>>>(cnt, x, node_idx, emb, W_in, b_in, z);

    // CSR by dst (shared by both layers); cur doubles as deg buffer first
    k_zerodeg<<<(NN + 255) / 256, 256, 0, stream>>>(cur);
    k_hist<<<(NE + 255) / 256, 256, 0, stream>>>(ei, cur);
    k_scan<<<1, 256, 0, stream>>>(cur, off, cur);
    k_fill<<<(NE + 255) / 256, 256, 0, stream>>>(cnt, ei, cur, esrc, ea_s, ea);

    // ---- layer 1 ----
    k_proj<<<NN / PROJ_J, 128, 0, stream>>>(cnt, z, Wl1, bl1, Wr1, br1, xl, xr);
    k_gat<<<NN, 128, 0, stream>>>(cnt, off, esrc, ea_s, We1, be1, att1, xl, xr, bo1, z, g1, beta1);

    // ---- layer 2 ----
    k_proj<<<NN / PROJ_J, 128, 0, stream>>>(cnt, z, Wl2, bl2, Wr2, br2, xl, xr);
    k_gat<<<NN, 128, 0, stream>>>(cnt, off, esrc, ea_s, We2, be2, att2, xl, xr, bo2, z, g2, beta2);

    k_head<<<NN, 64, 0, stream>>>(cnt, z, W_out, b_out, d_out);
}

// Round 7
// 606.769 us; speedup vs baseline: 2.6243x; 1.2528x over previous
//
#include <hip/hip_runtime.h>
#include <hip/hip_bf16.h>

#define NN 50000
#define NE 600000
#define IND 16
#define EDD 8
#define HIDD 128
#define NH 4
#define CC 32
#define EMBD 64
#define FEATD 64

typedef __hip_bfloat16 bf16;
typedef __attribute__((ext_vector_type(8))) short bshort8;
typedef __attribute__((ext_vector_type(4))) float floatx4;

__device__ __forceinline__ float b2f(bf16 v) { return __bfloat162float(v); }

// round-to-nearest-even f32 -> bf16 bits (matches __float2bfloat16 for finite values)
__device__ __forceinline__ unsigned short f2bu(float f) {
    unsigned int u = __float_as_uint(f);
    u += 0x7fffu + ((u >> 16) & 1u);
    return (unsigned short)(u >> 16);
}

template <bool F32>
__device__ __forceinline__ float LD(const void* p, long long i) {
    if constexpr (F32) return ((const float*)p)[i];
    else return __bfloat162float(((const bf16*)p)[i]);
}

// ---- dtype detector (fp32 misread as bf16 shows ~2^-8 rate of exp==0xFF halfwords)
__global__ void k_zero(int* __restrict__ cnt) { *cnt = 0; }

__global__ void k_detect(const unsigned short* __restrict__ x, int nhalf, int* __restrict__ cnt) {
    __shared__ int c;
    if (threadIdx.x == 0) c = 0;
    __syncthreads();
    int i = blockIdx.x * blockDim.x + threadIdx.x;
    int hits = 0;
    for (; i < nhalf; i += gridDim.x * blockDim.x)
        if ((x[i] & 0x7F80u) == 0x7F80u) hits++;
    if (hits) atomicAdd(&c, hits);
    __syncthreads();
    if (threadIdx.x == 0 && c) atomicAdd(cnt, c);
}

__device__ __forceinline__ bool is_f32(const int* cnt) { return *cnt > 8; }

// ---- CSR build: counting sort of edges by dst ----
__global__ void k_zerodeg(int* __restrict__ deg) {
    int i = blockIdx.x * blockDim.x + threadIdx.x;
    if (i < NN) deg[i] = 0;
}
__global__ void k_hist(const int* __restrict__ ei, int* __restrict__ deg) {
    int e = blockIdx.x * blockDim.x + threadIdx.x;
    if (e < NE) atomicAdd(&deg[ei[NE + e]], 1);
}
__global__ void k_scan(const int* __restrict__ deg, int* __restrict__ off, int* __restrict__ cur) {
    __shared__ int sums[256];
    int t = threadIdx.x;
    const int chunk = (NN + 255) / 256;
    int lo = t * chunk, hi = min(lo + chunk, NN);
    int s = 0;
    for (int i = lo; i < hi; i++) s += deg[i];
    sums[t] = s;
    __syncthreads();
    for (int o = 1; o < 256; o <<= 1) {
        int v = (t >= o) ? sums[t - o] : 0;
        __syncthreads();
        if (t >= o) sums[t] += v;
        __syncthreads();
    }
    int run = (t == 0) ? 0 : sums[t - 1];
    for (int i = lo; i < hi; i++) {
        off[i] = run; cur[i] = run;
        run += deg[i];
    }
    if (t == 255) off[NN] = run;
}
// esrc[slot]=src ; ea8[slot]=edge_attr as 8 packed bf16 (CSR-sorted, shared by both layers)
template <bool F32>
__device__ void fill_impl(const int* __restrict__ ei, int* __restrict__ cur,
                          int* __restrict__ esrc, uint4* __restrict__ ea8, const void* ea) {
    int e = blockIdx.x * blockDim.x + threadIdx.x;
    if (e >= NE) return;
    int slot = atomicAdd(&cur[ei[NE + e]], 1);
    esrc[slot] = ei[e];
    unsigned int w[4];
    #pragma unroll
    for (int d = 0; d < 4; d++) {
        unsigned int lo = f2bu(LD<F32>(ea, (long long)e * EDD + 2 * d));
        unsigned int hi = f2bu(LD<F32>(ea, (long long)e * EDD + 2 * d + 1));
        w[d] = lo | (hi << 16);
    }
    uint4 v; v.x = w[0]; v.y = w[1]; v.z = w[2]; v.w = w[3];
    ea8[slot] = v;
}
__global__ void k_fill(const int* cnt, const int* ei, int* cur, int* esrc, uint4* ea8,
                       const void* ea) {
    if (is_f32(cnt)) fill_impl<true>(ei, cur, esrc, ea8, ea);
    else             fill_impl<false>(ei, cur, esrc, ea8, ea);
}

// ---- z[n] = concat(relu(x[n] @ W_in + b_in), emb[node_idx[n]]) ; also bf16 shadow zb
template <bool F32>
__device__ void build_z_impl(const void* x, const int* __restrict__ node_idx, const void* emb,
                             const void* W_in, const void* b_in, float* __restrict__ z,
                             bf16* __restrict__ zb) {
    int n = blockIdx.x, t = threadIdx.x;  // 128
    float val;
    if (t < FEATD) {
        float acc = LD<F32>(b_in, t);
        #pragma unroll
        for (int k = 0; k < IND; k++)
            acc += LD<F32>(x, (long long)n * IND + k) * LD<F32>(W_in, k * FEATD + t);
        val = fmaxf(acc, 0.f);
    } else {
        val = LD<F32>(emb, (long long)node_idx[n] * EMBD + (t - FEATD));
    }
    z[n * HIDD + t] = val;
    zb[n * HIDD + t] = __float2bfloat16(val);
}
__global__ void k_build_z(const int* cnt, const void* x, const int* node_idx, const void* emb,
                          const void* W_in, const void* b_in, float* z, bf16* zb) {
    if (is_f32(cnt)) build_z_impl<true>(x, node_idx, emb, W_in, b_in, z, zb);
    else             build_z_impl<false>(x, node_idx, emb, W_in, b_in, z, zb);
}

// ---- weight prep: wbT[n][k] = [Wl|Wr][k][n] in bf16 (n-major), bias[n] = [bl|br]
template <bool F32>
__device__ void prepw_impl(const void* Wl, const void* bl, const void* Wr, const void* br,
                           bf16* __restrict__ wbT, float* __restrict__ bias) {
    int n = blockIdx.x;   // 256
    int k = threadIdx.x;  // 128
    float w = (n < HIDD) ? LD<F32>(Wl, k * HIDD + n) : LD<F32>(Wr, k * HIDD + (n - HIDD));
    wbT[n * HIDD + k] = __float2bfloat16(w);
    if (k == 0) bias[n] = (n < HIDD) ? LD<F32>(bl, n) : LD<F32>(br, n - HIDD);
}
__global__ void k_prepw(const int* cnt, const void* Wl, const void* bl, const void* Wr,
                        const void* br, bf16* wbT, float* bias) {
    if (is_f32(cnt)) prepw_impl<true>(Wl, bl, Wr, br, wbT, bias);
    else             prepw_impl<false>(Wl, bl, Wr, br, wbT, bias);
}

// ---- MFMA projection: [xl|xr] = zb @ wbT^T + bias.
// Block: 4 waves, M-tile 16 nodes; wave w covers output cols [w*64, w*64+64).
// A frag: lane holds zb[m0+(lane&15)][ks + (lane>>4)*8 + j], j=0..8  (16B contiguous)
// B frag: lane holds wbT[n][ks + (lane>>4)*8 + j] with n = n0+(lane&15)
// C/D:    col = lane&15, row = (lane>>4)*4 + reg   [m89/m91-verified layout]
__global__ __launch_bounds__(256) void k_projmm(const bf16* __restrict__ zb,
                                                const bf16* __restrict__ wbT,
                                                const float* __restrict__ bias,
                                                bf16* __restrict__ xl, bf16* __restrict__ xr) {
    int wave = threadIdx.x >> 6, lane = threadIdx.x & 63;
    int m0 = blockIdx.x * 16;
    int n0 = wave * 64;
    int l15 = lane & 15, q = lane >> 4;
    const bf16* arow = zb + ((m0 + l15) << 7) + q * 8;
    floatx4 acc0 = {0.f, 0.f, 0.f, 0.f}, acc1 = acc0, acc2 = acc0, acc3 = acc0;
    #pragma unroll
    for (int ks = 0; ks < HIDD; ks += 32) {
        bshort8 a  = *(const bshort8*)(arow + ks);
        bshort8 b0 = *(const bshort8*)(wbT + ((n0 + l15) << 7) + ks + q * 8);
        bshort8 b1 = *(const bshort8*)(wbT + ((n0 + 16 + l15) << 7) + ks + q * 8);
        bshort8 b2 = *(const bshort8*)(wbT + ((n0 + 32 + l15) << 7) + ks + q * 8);
        bshort8 b3 = *(const bshort8*)(wbT + ((n0 + 48 + l15) << 7) + ks + q * 8);
        acc0 = __builtin_amdgcn_mfma_f32_16x16x32_bf16(a, b0, acc0, 0, 0, 0);
        acc1 = __builtin_amdgcn_mfma_f32_16x16x32_bf16(a, b1, acc1, 0, 0, 0);
        acc2 = __builtin_amdgcn_mfma_f32_16x16x32_bf16(a, b2, acc2, 0, 0, 0);
        acc3 = __builtin_amdgcn_mfma_f32_16x16x32_bf16(a, b3, acc3, 0, 0, 0);
    }
    floatx4 accs[4] = {acc0, acc1, acc2, acc3};
    #pragma unroll
    for (int j = 0; j < 4; j++) {
        int colg = n0 + j * 16 + l15;
        float bv = bias[colg];
        bf16* dst = (colg < HIDD) ? (xl + colg) : (xr + (colg - HIDD));
        #pragma unroll
        for (int r = 0; r < 4; r++) {
            int rowc = m0 + q * 4 + r;
            dst[rowc << 7] = __float2bfloat16(accs[j][r] + bv);
        }
    }
}

// ---- fused GAT layer: 1 wave per dst node, 2 channels per lane, barrier-free LN
template <bool F32>
__device__ void gat_impl(const int* __restrict__ off, const int* __restrict__ esrc,
                         const uint4* __restrict__ ea8,
                         const void* We, const void* be, const void* att,
                         const bf16* __restrict__ xl, const bf16* __restrict__ xr,
                         const void* bo, float* __restrict__ z, bf16* __restrict__ zb,
                         const void* g, const void* beta) {
    int wave = threadIdx.x >> 6, lane = threadIdx.x & 63;
    int n = blockIdx.x * 2 + wave;
    int c0 = lane << 1;  // channels c0, c0+1 ; head = lane>>4 (16-lane groups)
    float wv0[EDD], wv1[EDD];
    #pragma unroll
    for (int d = 0; d < EDD; d++) {
        wv0[d] = LD<F32>(We, d * HIDD + c0);
        wv1[d] = LD<F32>(We, d * HIDD + c0 + 1);
    }
    float be0 = LD<F32>(be, c0), be1 = LD<F32>(be, c0 + 1);
    float at0 = LD<F32>(att, c0), at1 = LD<F32>(att, c0 + 1);
    unsigned int xru = *(const unsigned int*)(xr + (n << 7) + c0);
    float xr0 = __uint_as_float(xru << 16);
    float xr1 = __uint_as_float(xru & 0xffff0000u);
    int lo = off[n], hi = off[n + 1];
    float acc0 = 0.f, acc1 = 0.f, den = 0.f;
    #pragma unroll 2
    for (int i = lo; i < hi; i++) {
        int src = esrc[i];            // sequential broadcast
        uint4 eu = ea8[i];            // sequential broadcast, 8 bf16
        unsigned int xu = *(const unsigned int*)(xl + (src << 7) + c0);  // 256B/wave gather
        float e0 = __uint_as_float(eu.x << 16), e1 = __uint_as_float(eu.x & 0xffff0000u);
        float e2 = __uint_as_float(eu.y << 16), e3 = __uint_as_float(eu.y & 0xffff0000u);
        float e4 = __uint_as_float(eu.z << 16), e5 = __uint_as_float(eu.z & 0xffff0000u);
        float e6 = __uint_as_float(eu.w << 16), e7 = __uint_as_float(eu.w & 0xffff0000u);
        float ee0 = be0 + e0 * wv0[0] + e1 * wv0[1] + e2 * wv0[2] + e3 * wv0[3]
                        + e4 * wv0[4] + e5 * wv0[5] + e6 * wv0[6] + e7 * wv0[7];
        float ee1 = be1 + e0 * wv1[0] + e1 * wv1[1] + e2 * wv1[2] + e3 * wv1[3]
                        + e4 * wv1[4] + e5 * wv1[5] + e6 * wv1[6] + e7 * wv1[7];
        float x0 = __uint_as_float(xu << 16);
        float x1 = __uint_as_float(xu & 0xffff0000u);
        float s0 = x0 + xr0 + ee0; s0 = (s0 >= 0.f) ? s0 : 0.2f * s0;
        float s1 = x1 + xr1 + ee1; s1 = (s1 >= 0.f) ? s1 : 0.2f * s1;
        float ls = s0 * at0 + s1 * at1;
        ls += __shfl_xor(ls, 1);
        ls += __shfl_xor(ls, 2);
        ls += __shfl_xor(ls, 4);
        ls += __shfl_xor(ls, 8);   // sum over 16-lane head group = 32 channels
        float ex = __expf(ls);
        acc0 += ex * x0; acc1 += ex * x1; den += ex;
    }
    float inv = (den > 0.f) ? 1.0f / den : 0.f;
    float hv0 = fmaxf(acc0 * inv + LD<F32>(bo, c0), 0.f);
    float hv1 = fmaxf(acc1 * inv + LD<F32>(bo, c0 + 1), 0.f);
    float2 zv = *(const float2*)(z + (n << 7) + c0);
    float v0 = zv.x + hv0;
    float v1 = zv.y + hv1;
    float s = v0 + v1;
    #pragma unroll
    for (int m = 32; m; m >>= 1) s += __shfl_xor(s, m);
    float mu = s * (1.f / HIDD);
    float d0 = v0 - mu, d1 = v1 - mu;
    float s2 = d0 * d0 + d1 * d1;
    #pragma unroll
    for (int m = 32; m; m >>= 1) s2 += __shfl_xor(s2, m);
    float rs = rsqrtf(s2 * (1.f / HIDD) + 1e-5f);
    float o0 = d0 * rs * LD<F32>(g, c0) + LD<F32>(beta, c0);
    float o1 = d1 * rs * LD<F32>(g, c0 + 1) + LD<F32>(beta, c0 + 1);
    float2 ov; ov.x = o0; ov.y = o1;
    *(float2*)(z + (n << 7) + c0) = ov;
    unsigned int pk = (unsigned int)f2bu(o0) | ((unsigned int)f2bu(o1) << 16);
    *(unsigned int*)(zb + (n << 7) + c0) = pk;
}
__global__ void k_gat(const int* cnt, const int* off, const int* esrc, const uint4* ea8,
                      const void* We, const void* be, const void* att,
                      const bf16* xl, const bf16* xr, const void* bo, float* z, bf16* zb,
                      const void* g, const void* beta) {
    if (is_f32(cnt)) gat_impl<true>(off, esrc, ea8, We, be, att, xl, xr, bo, z, zb, g, beta);
    else             gat_impl<false>(off, esrc, ea8, We, be, att, xl, xr, bo, z, zb, g, beta);
}

// ---- out[n] = z[n] @ W_out + b_out
template <bool F32>
__device__ void head_impl(const float* __restrict__ z, const void* Wo, const void* bo, void* out) {
    int n = blockIdx.x;
    int lane = threadIdx.x;  // 64
    float acc = z[n * HIDD + lane] * LD<F32>(Wo, lane) +
                z[n * HIDD + 64 + lane] * LD<F32>(Wo, 64 + lane);
    #pragma unroll
    for (int o = 32; o; o >>= 1) acc += __shfl_down(acc, o);
    if (lane == 0) {
        float r = acc + LD<F32>(bo, 0);
        if constexpr (F32) ((float*)out)[n] = r;
        else               ((bf16*)out)[n] = __float2bfloat16(r);
    }
}
__global__ void k_head(const int* cnt, const float* z, const void* Wo, const void* bo, void* out) {
    if (is_f32(cnt)) head_impl<true>(z, Wo, bo, out);
    else             head_impl<false>(z, Wo, bo, out);
}

extern "C" void kernel_launch(void* const* d_in, const int* in_sizes, int n_in,
                              void* d_out, int out_size, void* d_ws, size_t ws_size,
                              hipStream_t stream) {
    const void* x        = d_in[0];
    const int*  node_idx = (const int*)d_in[1];
    const int*  ei       = (const int*)d_in[2];
    const void* ea       = d_in[3];
    const void* emb      = d_in[4];
    const void* W_in     = d_in[5];
    const void* b_in     = d_in[6];
    const void* Wl1 = d_in[7];  const void* bl1 = d_in[8];
    const void* Wr1 = d_in[9];  const void* br1 = d_in[10];
    const void* We1 = d_in[11]; const void* be1 = d_in[12];
    const void* att1 = d_in[13]; const void* bo1 = d_in[14];
    const void* Wl2 = d_in[15]; const void* bl2 = d_in[16];
    const void* Wr2 = d_in[17]; const void* br2 = d_in[18];
    const void* We2 = d_in[19]; const void* be2 = d_in[20];
    const void* att2 = d_in[21]; const void* bo2 = d_in[22];
    const void* g1 = d_in[23]; const void* beta1 = d_in[24];
    const void* g2 = d_in[25]; const void* beta2 = d_in[26];
    const void* W_out = d_in[27]; const void* b_out = d_in[28];

    // workspace (~76.5 MB), 16B-aligned sections:
    // cnt | z f32 | ea8 uint4 | wbT bf16 | bias f32 | zb bf16 | xl bf16 | xr bf16 | ints
    int*   cnt  = (int*)d_ws;
    float* z    = (float*)d_ws + 64;                       // NN*HIDD f32
    uint4* ea8  = (uint4*)(z + NN * HIDD);                 // NE uint4
    bf16*  wbT  = (bf16*)(ea8 + NE);                       // 256*128 bf16
    float* bias = (float*)(wbT + 2 * HIDD * HIDD);         // 256 f32
    bf16*  zb   = (bf16*)(bias + 2 * HIDD);                // NN*HIDD
    bf16*  xl   = zb + NN * HIDD;                          // NN*HIDD
    bf16*  xr   = xl + NN * HIDD;                          // NN*HIDD
    int*   off  = (int*)(xr + NN * HIDD);                  // NN+1
    int*   cur  = off + NN + 1;                            // NN
    int*   esrc = cur + NN;                                // NE

    int nhalf = in_sizes[0] < 65536 ? in_sizes[0] : 65536;
    k_zero<<<1, 1, 0, stream>>>(cnt);
    k_detect<<<64, 256, 0, stream>>>((const unsigned short*)x, nhalf, cnt);
    k_build_z<<<NN, 128, 0, stream>>>(cnt, x, node_idx, emb, W_in, b_in, z, zb);

    // CSR by dst (shared by both layers); cur doubles as deg buffer first
    k_zerodeg<<<(NN + 255) / 256, 256, 0, stream>>>(cur);
    k_hist<<<(NE + 255) / 256, 256, 0, stream>>>(ei, cur);
    k_scan<<<1, 256, 0, stream>>>(cur, off, cur);
    k_fill<<<(NE + 255) / 256, 256, 0, stream>>>(cnt, ei, cur, esrc, ea8, ea);

    // ---- layer 1 ----
    k_prepw<<<2 * HIDD, HIDD, 0, stream>>>(cnt, Wl1, bl1, Wr1, br1, wbT, bias);
    k_projmm<<<NN / 16, 256, 0, stream>>>(zb, wbT, bias, xl, xr);
    k_gat<<<NN / 2, 128, 0, stream>>>(cnt, off, esrc, ea8, We1, be1, att1, xl, xr, bo1, z, zb, g1, beta1);

    // ---- layer 2 ----
    k_prepw<<<2 * HIDD, HIDD, 0, stream>>>(cnt, Wl2, bl2, Wr2, br2, wbT, bias);
    k_projmm<<<NN / 16, 256, 0, stream>>>(zb, wbT, bias, xl, xr);
    k_gat<<<NN / 2, 128, 0, stream>>>(cnt, off, esrc, ea8, We2, be2, att2, xl, xr, bo2, z, zb, g2, beta2);

    k_head<<<NN, 64, 0, stream>>>(cnt, z, W_out, b_out, d_out);
}

// Round 8
// 492.217 us; speedup vs baseline: 3.2350x; 1.2327x over previous
//
#include <hip/hip_runtime.h>
#include <hip/hip_bf16.h>

#define NN 50000
#define NE 600000
#define IND 16
#define EDD 8
#define HIDD 128
#define NH 4
#define CC 32
#define EMBD 64
#define FEATD 64
#define NB_SCAN ((NN + 255) / 256)  // 196

typedef __hip_bfloat16 bf16;
typedef __attribute__((ext_vector_type(8))) short bshort8;
typedef __attribute__((ext_vector_type(4))) float floatx4;

__device__ __forceinline__ float b2f(bf16 v) { return __bfloat162float(v); }

// round-to-nearest-even f32 -> bf16 bits
__device__ __forceinline__ unsigned short f2bu(float f) {
    unsigned int u = __float_as_uint(f);
    u += 0x7fffu + ((u >> 16) & 1u);
    return (unsigned short)(u >> 16);
}

template <bool F32>
__device__ __forceinline__ float LD(const void* p, long long i) {
    if constexpr (F32) return ((const float*)p)[i];
    else return __bfloat162float(((const bf16*)p)[i]);
}

// ---- zero cnt + deg in one launch
__global__ void k_init0(int* __restrict__ cnt, int* __restrict__ deg) {
    int i = blockIdx.x * blockDim.x + threadIdx.x;
    if (i == 0) *cnt = 0;
    if (i < NN) deg[i] = 0;
}

// ---- dtype detector (fp32 misread as bf16 shows ~2^-8 rate of exp==0xFF halfwords)
__global__ void k_detect(const unsigned short* __restrict__ x, int nhalf, int* __restrict__ cnt) {
    __shared__ int c;
    if (threadIdx.x == 0) c = 0;
    __syncthreads();
    int i = blockIdx.x * blockDim.x + threadIdx.x;
    int hits = 0;
    for (; i < nhalf; i += gridDim.x * blockDim.x)
        if ((x[i] & 0x7F80u) == 0x7F80u) hits++;
    if (hits) atomicAdd(&c, hits);
    __syncthreads();
    if (threadIdx.x == 0 && c) atomicAdd(cnt, c);
}

__device__ __forceinline__ bool is_f32(const int* cnt) { return *cnt > 8; }

// ---- CSR build: counting sort of edges by dst ----
__global__ void k_hist(const int* __restrict__ ei, int* __restrict__ deg) {
    int e = blockIdx.x * blockDim.x + threadIdx.x;
    if (e < NE) atomicAdd(&deg[ei[NE + e]], 1);
}

// level 1: per-tile exclusive scan (local) + block totals
__global__ void k_scan1(const int* __restrict__ deg, int* __restrict__ off,
                        int* __restrict__ bsum) {
    __shared__ int tile[256];
    int t = threadIdx.x;
    int gid = blockIdx.x * 256 + t;
    int v = (gid < NN) ? deg[gid] : 0;
    tile[t] = v;
    __syncthreads();
    #pragma unroll
    for (int o = 1; o < 256; o <<= 1) {
        int u = (t >= o) ? tile[t - o] : 0;
        __syncthreads();
        tile[t] += u;
        __syncthreads();
    }
    if (gid < NN) off[gid] = tile[t] - v;  // exclusive, local to tile
    if (t == 255) bsum[blockIdx.x] = tile[255];
}
// level 2: single tiny block scans the 196 block sums -> exclusive
__global__ void k_scan2(int* __restrict__ bsum) {
    __shared__ int tile[256];
    int t = threadIdx.x;
    int v = (t < NB_SCAN) ? bsum[t] : 0;
    tile[t] = v;
    __syncthreads();
    #pragma unroll
    for (int o = 1; o < 256; o <<= 1) {
        int u = (t >= o) ? tile[t - o] : 0;
        __syncthreads();
        tile[t] += u;
        __syncthreads();
    }
    if (t < NB_SCAN) bsum[t] = tile[t] - v;  // exclusive
}
// level 3: add block offset; produce final off + working cur; off[NN]=NE
__global__ void k_scan3(int* __restrict__ off, const int* __restrict__ bsum,
                        int* __restrict__ cur) {
    int gid = blockIdx.x * 256 + threadIdx.x;
    if (gid < NN) {
        int o = off[gid] + bsum[blockIdx.x];
        off[gid] = o;
        cur[gid] = o;
    }
    if (gid == 0) off[NN] = NE;
}

// esrc[slot]=src ; ea8[slot]=edge_attr as 8 packed bf16 (CSR-sorted, shared by both layers)
template <bool F32>
__device__ void fill_impl(const int* __restrict__ ei, int* __restrict__ cur,
                          int* __restrict__ esrc, uint4* __restrict__ ea8, const void* ea) {
    int e = blockIdx.x * blockDim.x + threadIdx.x;
    if (e >= NE) return;
    int slot = atomicAdd(&cur[ei[NE + e]], 1);
    esrc[slot] = ei[e];
    unsigned int w[4];
    #pragma unroll
    for (int d = 0; d < 4; d++) {
        unsigned int lo = f2bu(LD<F32>(ea, (long long)e * EDD + 2 * d));
        unsigned int hi = f2bu(LD<F32>(ea, (long long)e * EDD + 2 * d + 1));
        w[d] = lo | (hi << 16);
    }
    uint4 v; v.x = w[0]; v.y = w[1]; v.z = w[2]; v.w = w[3];
    ea8[slot] = v;
}
__global__ void k_fill(const int* cnt, const int* ei, int* cur, int* esrc, uint4* ea8,
                       const void* ea) {
    if (is_f32(cnt)) fill_impl<true>(ei, cur, esrc, ea8, ea);
    else             fill_impl<false>(ei, cur, esrc, ea8, ea);
}

// ---- z[n] = concat(relu(x[n] @ W_in + b_in), emb[node_idx[n]]) ; also bf16 shadow zb
template <bool F32>
__device__ void build_z_impl(const void* x, const int* __restrict__ node_idx, const void* emb,
                             const void* W_in, const void* b_in, float* __restrict__ z,
                             bf16* __restrict__ zb) {
    int n = blockIdx.x, t = threadIdx.x;  // 128
    float val;
    if (t < FEATD) {
        float acc = LD<F32>(b_in, t);
        #pragma unroll
        for (int k = 0; k < IND; k++)
            acc += LD<F32>(x, (long long)n * IND + k) * LD<F32>(W_in, k * FEATD + t);
        val = fmaxf(acc, 0.f);
    } else {
        val = LD<F32>(emb, (long long)node_idx[n] * EMBD + (t - FEATD));
    }
    z[n * HIDD + t] = val;
    zb[n * HIDD + t] = __float2bfloat16(val);
}
__global__ void k_build_z(const int* cnt, const void* x, const int* node_idx, const void* emb,
                          const void* W_in, const void* b_in, float* z, bf16* zb) {
    if (is_f32(cnt)) build_z_impl<true>(x, node_idx, emb, W_in, b_in, z, zb);
    else             build_z_impl<false>(x, node_idx, emb, W_in, b_in, z, zb);
}

// ---- weight prep: wbT[n][k] = [Wl|Wr][k][n] in bf16 (n-major), bias[n] = [bl|br]
template <bool F32>
__device__ void prepw_impl(const void* Wl, const void* bl, const void* Wr, const void* br,
                           bf16* __restrict__ wbT, float* __restrict__ bias) {
    int n = blockIdx.x;   // 256
    int k = threadIdx.x;  // 128
    float w = (n < HIDD) ? LD<F32>(Wl, k * HIDD + n) : LD<F32>(Wr, k * HIDD + (n - HIDD));
    wbT[n * HIDD + k] = __float2bfloat16(w);
    if (k == 0) bias[n] = (n < HIDD) ? LD<F32>(bl, n) : LD<F32>(br, n - HIDD);
}
__global__ void k_prepw(const int* cnt, const void* Wl, const void* bl, const void* Wr,
                        const void* br, bf16* wbT, float* bias) {
    if (is_f32(cnt)) prepw_impl<true>(Wl, bl, Wr, br, wbT, bias);
    else             prepw_impl<false>(Wl, bl, Wr, br, wbT, bias);
}

// ---- MFMA projection: [xl|xr] = zb @ wbT^T + bias (16x16x32 bf16, verified layouts)
__global__ __launch_bounds__(256) void k_projmm(const bf16* __restrict__ zb,
                                                const bf16* __restrict__ wbT,
                                                const float* __restrict__ bias,
                                                bf16* __restrict__ xl, bf16* __restrict__ xr) {
    int wave = threadIdx.x >> 6, lane = threadIdx.x & 63;
    int m0 = blockIdx.x * 16;
    int n0 = wave * 64;
    int l15 = lane & 15, q = lane >> 4;
    const bf16* arow = zb + ((m0 + l15) << 7) + q * 8;
    floatx4 acc0 = {0.f, 0.f, 0.f, 0.f}, acc1 = acc0, acc2 = acc0, acc3 = acc0;
    #pragma unroll
    for (int ks = 0; ks < HIDD; ks += 32) {
        bshort8 a  = *(const bshort8*)(arow + ks);
        bshort8 b0 = *(const bshort8*)(wbT + ((n0 + l15) << 7) + ks + q * 8);
        bshort8 b1 = *(const bshort8*)(wbT + ((n0 + 16 + l15) << 7) + ks + q * 8);
        bshort8 b2 = *(const bshort8*)(wbT + ((n0 + 32 + l15) << 7) + ks + q * 8);
        bshort8 b3 = *(const bshort8*)(wbT + ((n0 + 48 + l15) << 7) + ks + q * 8);
        acc0 = __builtin_amdgcn_mfma_f32_16x16x32_bf16(a, b0, acc0, 0, 0, 0);
        acc1 = __builtin_amdgcn_mfma_f32_16x16x32_bf16(a, b1, acc1, 0, 0, 0);
        acc2 = __builtin_amdgcn_mfma_f32_16x16x32_bf16(a, b2, acc2, 0, 0, 0);
        acc3 = __builtin_amdgcn_mfma_f32_16x16x32_bf16(a, b3, acc3, 0, 0, 0);
    }
    floatx4 accs[4] = {acc0, acc1, acc2, acc3};
    #pragma unroll
    for (int j = 0; j < 4; j++) {
        int colg = n0 + j * 16 + l15;
        float bv = bias[colg];
        bf16* dst = (colg < HIDD) ? (xl + colg) : (xr + (colg - HIDD));
        #pragma unroll
        for (int r = 0; r < 4; r++) {
            int rowc = m0 + q * 4 + r;
            dst[rowc << 7] = __float2bfloat16(accs[j][r] + bv);
        }
    }
}

// ---- fused GAT layer: 1 wave per dst node, 2 channels per lane, barrier-free LN
template <bool F32>
__device__ void gat_impl(const int* __restrict__ off, const int* __restrict__ esrc,
                         const uint4* __restrict__ ea8,
                         const void* We, const void* be, const void* att,
                         const bf16* __restrict__ xl, const bf16* __restrict__ xr,
                         const void* bo, float* __restrict__ z, bf16* __restrict__ zb,
                         const void* g, const void* beta) {
    int wave = threadIdx.x >> 6, lane = threadIdx.x & 63;
    int n = blockIdx.x * 2 + wave;
    int c0 = lane << 1;  // channels c0, c0+1 ; head = lane>>4 (16-lane groups)
    float wv0[EDD], wv1[EDD];
    #pragma unroll
    for (int d = 0; d < EDD; d++) {
        wv0[d] = LD<F32>(We, d * HIDD + c0);
        wv1[d] = LD<F32>(We, d * HIDD + c0 + 1);
    }
    float be0 = LD<F32>(be, c0), be1 = LD<F32>(be, c0 + 1);
    float at0 = LD<F32>(att, c0), at1 = LD<F32>(att, c0 + 1);
    unsigned int xru = *(const unsigned int*)(xr + (n << 7) + c0);
    float xr0 = __uint_as_float(xru << 16);
    float xr1 = __uint_as_float(xru & 0xffff0000u);
    int lo = off[n], hi = off[n + 1];
    float acc0 = 0.f, acc1 = 0.f, den = 0.f;
    #pragma unroll 2
    for (int i = lo; i < hi; i++) {
        int src = esrc[i];            // sequential broadcast
        uint4 eu = ea8[i];            // sequential broadcast, 8 bf16
        unsigned int xu = *(const unsigned int*)(xl + (src << 7) + c0);  // 256B/wave gather
        float e0 = __uint_as_float(eu.x << 16), e1 = __uint_as_float(eu.x & 0xffff0000u);
        float e2 = __uint_as_float(eu.y << 16), e3 = __uint_as_float(eu.y & 0xffff0000u);
        float e4 = __uint_as_float(eu.z << 16), e5 = __uint_as_float(eu.z & 0xffff0000u);
        float e6 = __uint_as_float(eu.w << 16), e7 = __uint_as_float(eu.w & 0xffff0000u);
        float ee0 = be0 + e0 * wv0[0] + e1 * wv0[1] + e2 * wv0[2] + e3 * wv0[3]
                        + e4 * wv0[4] + e5 * wv0[5] + e6 * wv0[6] + e7 * wv0[7];
        float ee1 = be1 + e0 * wv1[0] + e1 * wv1[1] + e2 * wv1[2] + e3 * wv1[3]
                        + e4 * wv1[4] + e5 * wv1[5] + e6 * wv1[6] + e7 * wv1[7];
        float x0 = __uint_as_float(xu << 16);
        float x1 = __uint_as_float(xu & 0xffff0000u);
        float s0 = x0 + xr0 + ee0; s0 = (s0 >= 0.f) ? s0 : 0.2f * s0;
        float s1 = x1 + xr1 + ee1; s1 = (s1 >= 0.f) ? s1 : 0.2f * s1;
        float ls = s0 * at0 + s1 * at1;
        ls += __shfl_xor(ls, 1);
        ls += __shfl_xor(ls, 2);
        ls += __shfl_xor(ls, 4);
        ls += __shfl_xor(ls, 8);   // sum over 16-lane head group = 32 channels
        float ex = __expf(ls);
        acc0 += ex * x0; acc1 += ex * x1; den += ex;
    }
    float inv = (den > 0.f) ? 1.0f / den : 0.f;
    float hv0 = fmaxf(acc0 * inv + LD<F32>(bo, c0), 0.f);
    float hv1 = fmaxf(acc1 * inv + LD<F32>(bo, c0 + 1), 0.f);
    float2 zv = *(const float2*)(z + (n << 7) + c0);
    float v0 = zv.x + hv0;
    float v1 = zv.y + hv1;
    float s = v0 + v1;
    #pragma unroll
    for (int m = 32; m; m >>= 1) s += __shfl_xor(s, m);
    float mu = s * (1.f / HIDD);
    float d0 = v0 - mu, d1 = v1 - mu;
    float s2 = d0 * d0 + d1 * d1;
    #pragma unroll
    for (int m = 32; m; m >>= 1) s2 += __shfl_xor(s2, m);
    float rs = rsqrtf(s2 * (1.f / HIDD) + 1e-5f);
    float o0 = d0 * rs * LD<F32>(g, c0) + LD<F32>(beta, c0);
    float o1 = d1 * rs * LD<F32>(g, c0 + 1) + LD<F32>(beta, c0 + 1);
    float2 ov; ov.x = o0; ov.y = o1;
    *(float2*)(z + (n << 7) + c0) = ov;
    unsigned int pk = (unsigned int)f2bu(o0) | ((unsigned int)f2bu(o1) << 16);
    *(unsigned int*)(zb + (n << 7) + c0) = pk;
}
__global__ void k_gat(const int* cnt, const int* off, const int* esrc, const uint4* ea8,
                      const void* We, const void* be, const void* att,
                      const bf16* xl, const bf16* xr, const void* bo, float* z, bf16* zb,
                      const void* g, const void* beta) {
    if (is_f32(cnt)) gat_impl<true>(off, esrc, ea8, We, be, att, xl, xr, bo, z, zb, g, beta);
    else             gat_impl<false>(off, esrc, ea8, We, be, att, xl, xr, bo, z, zb, g, beta);
}

// ---- out[n] = z[n] @ W_out + b_out  (4 nodes per block, one wave each)
template <bool F32>
__device__ void head_impl(const float* __restrict__ z, const void* Wo, const void* bo, void* out) {
    int wave = threadIdx.x >> 6, lane = threadIdx.x & 63;
    int n = blockIdx.x * 4 + wave;
    float acc = z[(long long)n * HIDD + lane] * LD<F32>(Wo, lane) +
                z[(long long)n * HIDD + 64 + lane] * LD<F32>(Wo, 64 + lane);
    #pragma unroll
    for (int o = 32; o; o >>= 1) acc += __shfl_down(acc, o);
    if (lane == 0) {
        float r = acc + LD<F32>(bo, 0);
        if constexpr (F32) ((float*)out)[n] = r;
        else               ((bf16*)out)[n] = __float2bfloat16(r);
    }
}
__global__ void k_head(const int* cnt, const float* z, const void* Wo, const void* bo, void* out) {
    if (is_f32(cnt)) head_impl<true>(z, Wo, bo, out);
    else             head_impl<false>(z, Wo, bo, out);
}

extern "C" void kernel_launch(void* const* d_in, const int* in_sizes, int n_in,
                              void* d_out, int out_size, void* d_ws, size_t ws_size,
                              hipStream_t stream) {
    const void* x        = d_in[0];
    const int*  node_idx = (const int*)d_in[1];
    const int*  ei       = (const int*)d_in[2];
    const void* ea       = d_in[3];
    const void* emb      = d_in[4];
    const void* W_in     = d_in[5];
    const void* b_in     = d_in[6];
    const void* Wl1 = d_in[7];  const void* bl1 = d_in[8];
    const void* Wr1 = d_in[9];  const void* br1 = d_in[10];
    const void* We1 = d_in[11]; const void* be1 = d_in[12];
    const void* att1 = d_in[13]; const void* bo1 = d_in[14];
    const void* Wl2 = d_in[15]; const void* bl2 = d_in[16];
    const void* Wr2 = d_in[17]; const void* br2 = d_in[18];
    const void* We2 = d_in[19]; const void* be2 = d_in[20];
    const void* att2 = d_in[21]; const void* bo2 = d_in[22];
    const void* g1 = d_in[23]; const void* beta1 = d_in[24];
    const void* g2 = d_in[25]; const void* beta2 = d_in[26];
    const void* W_out = d_in[27]; const void* b_out = d_in[28];

    // workspace (~76.5 MB), 16B-aligned sections:
    int*   cnt  = (int*)d_ws;
    float* z    = (float*)d_ws + 64;                       // NN*HIDD f32
    uint4* ea8  = (uint4*)(z + NN * HIDD);                 // NE uint4
    bf16*  wbT  = (bf16*)(ea8 + NE);                       // 256*128 bf16
    float* bias = (float*)(wbT + 2 * HIDD * HIDD);         // 256 f32
    bf16*  zb   = (bf16*)(bias + 2 * HIDD);                // NN*HIDD
    bf16*  xl   = zb + NN * HIDD;                          // NN*HIDD
    bf16*  xr   = xl + NN * HIDD;                          // NN*HIDD
    int*   off  = (int*)(xr + NN * HIDD);                  // NN+1
    int*   cur  = off + NN + 1;                            // NN (doubles as deg)
    int*   esrc = cur + NN;                                // NE
    int*   bsum = esrc + NE;                               // NB_SCAN

    int nhalf = in_sizes[0] < 65536 ? in_sizes[0] : 65536;
    k_init0<<<(NN + 255) / 256, 256, 0, stream>>>(cnt, cur);
    k_detect<<<64, 256, 0, stream>>>((const unsigned short*)x, nhalf, cnt);
    k_build_z<<<NN, 128, 0, stream>>>(cnt, x, node_idx, emb, W_in, b_in, z, zb);

    // CSR by dst (shared by both layers); cur doubles as deg buffer first
    k_hist<<<(NE + 255) / 256, 256, 0, stream>>>(ei, cur);
    k_scan1<<<NB_SCAN, 256, 0, stream>>>(cur, off, bsum);
    k_scan2<<<1, 256, 0, stream>>>(bsum);
    k_scan3<<<NB_SCAN, 256, 0, stream>>>(off, bsum, cur);
    k_fill<<<(NE + 255) / 256, 256, 0, stream>>>(cnt, ei, cur, esrc, ea8, ea);

    // ---- layer 1 ----
    k_prepw<<<2 * HIDD, HIDD, 0, stream>>>(cnt, Wl1, bl1, Wr1, br1, wbT, bias);
    k_projmm<<<NN / 16, 256, 0, stream>>>(zb, wbT, bias, xl, xr);
    k_gat<<<NN / 2, 128, 0, stream>>>(cnt, off, esrc, ea8, We1, be1, att1, xl, xr, bo1, z, zb, g1, beta1);

    // ---- layer 2 ----
    k_prepw<<<2 * HIDD, HIDD, 0, stream>>>(cnt, Wl2, bl2, Wr2, br2, wbT, bias);
    k_projmm<<<NN / 16, 256, 0, stream>>>(zb, wbT, bias, xl, xr);
    k_gat<<<NN / 2, 128, 0, stream>>>(cnt, off, esrc, ea8, We2, be2, att2, xl, xr, bo2, z, zb, g2, beta2);

    k_head<<<NN / 4 + 1, 256, 0, stream>>>(cnt, z, W_out, b_out, d_out);
}

// Round 9
// 462.390 us; speedup vs baseline: 3.4437x; 1.0645x over previous
//
#include <hip/hip_runtime.h>
#include <hip/hip_bf16.h>

#define NN 50000
#define NE 600000
#define IND 16
#define EDD 8
#define HIDD 128
#define NH 4
#define CC 32
#define EMBD 64
#define FEATD 64
#define NB_SCAN ((NN + 255) / 256)  // 196

typedef __hip_bfloat16 bf16;
typedef __attribute__((ext_vector_type(8))) short bshort8;
typedef __attribute__((ext_vector_type(4))) float floatx4;

__device__ __forceinline__ float b2f(bf16 v) { return __bfloat162float(v); }

// round-to-nearest-even f32 -> bf16 bits
__device__ __forceinline__ unsigned short f2bu(float f) {
    unsigned int u = __float_as_uint(f);
    u += 0x7fffu + ((u >> 16) & 1u);
    return (unsigned short)(u >> 16);
}

template <bool F32>
__device__ __forceinline__ float LD(const void* p, long long i) {
    if constexpr (F32) return ((const float*)p)[i];
    else return __bfloat162float(((const bf16*)p)[i]);
}

// ---- zero cnt + deg in one launch
__global__ void k_init0(int* __restrict__ cnt, int* __restrict__ deg) {
    int i = blockIdx.x * blockDim.x + threadIdx.x;
    if (i == 0) *cnt = 0;
    if (i < NN) deg[i] = 0;
}

// ---- dtype detector (fp32 misread as bf16 shows ~2^-8 rate of exp==0xFF halfwords)
__global__ void k_detect(const unsigned short* __restrict__ x, int nhalf, int* __restrict__ cnt) {
    __shared__ int c;
    if (threadIdx.x == 0) c = 0;
    __syncthreads();
    int i = blockIdx.x * blockDim.x + threadIdx.x;
    int hits = 0;
    for (; i < nhalf; i += gridDim.x * blockDim.x)
        if ((x[i] & 0x7F80u) == 0x7F80u) hits++;
    if (hits) atomicAdd(&c, hits);
    __syncthreads();
    if (threadIdx.x == 0 && c) atomicAdd(cnt, c);
}

__device__ __forceinline__ bool is_f32(const int* cnt) { return *cnt > 8; }

// ---- CSR: histogram also records each edge's rank within its dst bucket
__global__ void k_hist(const int* __restrict__ ei, int* __restrict__ deg, int* __restrict__ rank) {
    int e = blockIdx.x * blockDim.x + threadIdx.x;
    if (e < NE) rank[e] = atomicAdd(&deg[ei[NE + e]], 1);
}

// level 1: per-tile exclusive scan (local) + block totals
__global__ void k_scan1(const int* __restrict__ deg, int* __restrict__ off,
                        int* __restrict__ bsum) {
    __shared__ int tile[256];
    int t = threadIdx.x;
    int gid = blockIdx.x * 256 + t;
    int v = (gid < NN) ? deg[gid] : 0;
    tile[t] = v;
    __syncthreads();
    #pragma unroll
    for (int o = 1; o < 256; o <<= 1) {
        int u = (t >= o) ? tile[t - o] : 0;
        __syncthreads();
        tile[t] += u;
        __syncthreads();
    }
    if (gid < NN) off[gid] = tile[t] - v;
    if (t == 255) bsum[blockIdx.x] = tile[255];
}
// level 2: single block scans the 196 block sums -> exclusive
__global__ void k_scan2(int* __restrict__ bsum) {
    __shared__ int tile[256];
    int t = threadIdx.x;
    int v = (t < NB_SCAN) ? bsum[t] : 0;
    tile[t] = v;
    __syncthreads();
    #pragma unroll
    for (int o = 1; o < 256; o <<= 1) {
        int u = (t >= o) ? tile[t - o] : 0;
        __syncthreads();
        tile[t] += u;
        __syncthreads();
    }
    if (t < NB_SCAN) bsum[t] = tile[t] - v;
}
// level 3: add block offset; off[NN]=NE
__global__ void k_scan3(int* __restrict__ off, const int* __restrict__ bsum) {
    int gid = blockIdx.x * 256 + threadIdx.x;
    if (gid < NN) off[gid] += bsum[blockIdx.x];
    if (gid == 0) off[NN] = NE;
}

// slot = off[dst] + rank[e] -> esrc + packed bf16 edge_attr, CSR-sorted. No atomics.
template <bool F32>
__device__ void fill_impl(const int* __restrict__ ei, const int* __restrict__ off,
                          const int* __restrict__ rank, int* __restrict__ esrc,
                          uint4* __restrict__ ea8, const void* ea) {
    int e = blockIdx.x * blockDim.x + threadIdx.x;
    if (e >= NE) return;
    int slot = off[ei[NE + e]] + rank[e];
    esrc[slot] = ei[e];
    unsigned int w[4];
    #pragma unroll
    for (int d = 0; d < 4; d++) {
        unsigned int lo = f2bu(LD<F32>(ea, (long long)e * EDD + 2 * d));
        unsigned int hi = f2bu(LD<F32>(ea, (long long)e * EDD + 2 * d + 1));
        w[d] = lo | (hi << 16);
    }
    uint4 v; v.x = w[0]; v.y = w[1]; v.z = w[2]; v.w = w[3];
    ea8[slot] = v;
}
__global__ void k_fill(const int* cnt, const int* ei, const int* off, const int* rank,
                       int* esrc, uint4* ea8, const void* ea) {
    if (is_f32(cnt)) fill_impl<true>(ei, off, rank, esrc, ea8, ea);
    else             fill_impl<false>(ei, off, rank, esrc, ea8, ea);
}

// ---- zb[n] = bf16(concat(relu(x[n] @ W_in + b_in), emb[node_idx[n]]))
template <bool F32>
__device__ void build_z_impl(const void* x, const int* __restrict__ node_idx, const void* emb,
                             const void* W_in, const void* b_in, bf16* __restrict__ zb) {
    int n = blockIdx.x, t = threadIdx.x;  // 128
    float val;
    if (t < FEATD) {
        float acc = LD<F32>(b_in, t);
        #pragma unroll
        for (int k = 0; k < IND; k++)
            acc += LD<F32>(x, (long long)n * IND + k) * LD<F32>(W_in, k * FEATD + t);
        val = fmaxf(acc, 0.f);
    } else {
        val = LD<F32>(emb, (long long)node_idx[n] * EMBD + (t - FEATD));
    }
    zb[n * HIDD + t] = __float2bfloat16(val);
}
__global__ void k_build_z(const int* cnt, const void* x, const int* node_idx, const void* emb,
                          const void* W_in, const void* b_in, bf16* zb) {
    if (is_f32(cnt)) build_z_impl<true>(x, node_idx, emb, W_in, b_in, zb);
    else             build_z_impl<false>(x, node_idx, emb, W_in, b_in, zb);
}

// ---- weight prep, BOTH layers in one launch: wbT[layer][n][k], bias[layer][n]
template <bool F32>
__device__ void prepw_impl(const void* Wl1, const void* bl1, const void* Wr1, const void* br1,
                           const void* Wl2, const void* bl2, const void* Wr2, const void* br2,
                           bf16* __restrict__ wbT, float* __restrict__ bias) {
    int layer = blockIdx.x >> 8;
    int n = blockIdx.x & 255;
    int k = threadIdx.x;  // 128
    const void* W = layer ? (n < HIDD ? Wl2 : Wr2) : (n < HIDD ? Wl1 : Wr1);
    const void* b = layer ? (n < HIDD ? bl2 : br2) : (n < HIDD ? bl1 : br1);
    int nn = n & (HIDD - 1);
    wbT[(layer * 256 + n) * HIDD + k] = __float2bfloat16(LD<F32>(W, k * HIDD + nn));
    if (k == 0) bias[layer * 256 + n] = LD<F32>(b, nn);
}
__global__ void k_prepw(const int* cnt,
                        const void* Wl1, const void* bl1, const void* Wr1, const void* br1,
                        const void* Wl2, const void* bl2, const void* Wr2, const void* br2,
                        bf16* wbT, float* bias) {
    if (is_f32(cnt)) prepw_impl<true>(Wl1, bl1, Wr1, br1, Wl2, bl2, Wr2, br2, wbT, bias);
    else             prepw_impl<false>(Wl1, bl1, Wr1, br1, Wl2, bl2, Wr2, br2, wbT, bias);
}

// ---- MFMA projection: [xl|xr] = zb @ wbT^T + bias (16x16x32 bf16, verified layouts)
__global__ __launch_bounds__(256) void k_projmm(const bf16* __restrict__ zb,
                                                const bf16* __restrict__ wbT,
                                                const float* __restrict__ bias,
                                                bf16* __restrict__ xl, bf16* __restrict__ xr) {
    int wave = threadIdx.x >> 6, lane = threadIdx.x & 63;
    int m0 = blockIdx.x * 16;
    int n0 = wave * 64;
    int l15 = lane & 15, q = lane >> 4;
    const bf16* arow = zb + ((m0 + l15) << 7) + q * 8;
    floatx4 acc0 = {0.f, 0.f, 0.f, 0.f}, acc1 = acc0, acc2 = acc0, acc3 = acc0;
    #pragma unroll
    for (int ks = 0; ks < HIDD; ks += 32) {
        bshort8 a  = *(const bshort8*)(arow + ks);
        bshort8 b0 = *(const bshort8*)(wbT + ((n0 + l15) << 7) + ks + q * 8);
        bshort8 b1 = *(const bshort8*)(wbT + ((n0 + 16 + l15) << 7) + ks + q * 8);
        bshort8 b2 = *(const bshort8*)(wbT + ((n0 + 32 + l15) << 7) + ks + q * 8);
        bshort8 b3 = *(const bshort8*)(wbT + ((n0 + 48 + l15) << 7) + ks + q * 8);
        acc0 = __builtin_amdgcn_mfma_f32_16x16x32_bf16(a, b0, acc0, 0, 0, 0);
        acc1 = __builtin_amdgcn_mfma_f32_16x16x32_bf16(a, b1, acc1, 0, 0, 0);
        acc2 = __builtin_amdgcn_mfma_f32_16x16x32_bf16(a, b2, acc2, 0, 0, 0);
        acc3 = __builtin_amdgcn_mfma_f32_16x16x32_bf16(a, b3, acc3, 0, 0, 0);
    }
    floatx4 accs[4] = {acc0, acc1, acc2, acc3};
    #pragma unroll
    for (int j = 0; j < 4; j++) {
        int colg = n0 + j * 16 + l15;
        float bv = bias[colg];
        bf16* dst = (colg < HIDD) ? (xl + colg) : (xr + (colg - HIDD));
        #pragma unroll
        for (int r = 0; r < 4; r++) {
            int rowc = m0 + q * 4 + r;
            dst[rowc << 7] = __float2bfloat16(accs[j][r] + bv);
        }
    }
}

// ---- fused GAT layer: 1 wave/node, 2 ch/lane, rotating prefetch, barrier-free LN.
// LAST: fuse output head (out = LN(...) @ W_out + b_out), skip zb write.
template <bool F32, bool LAST>
__device__ void gat_impl(const int* __restrict__ off, const int* __restrict__ esrc,
                         const uint4* __restrict__ ea8,
                         const void* We, const void* be, const void* att,
                         const bf16* __restrict__ xl, const bf16* __restrict__ xr,
                         const void* bo, bf16* __restrict__ zb,
                         const void* g, const void* beta,
                         const void* Wo, const void* bout, void* out) {
    int wave = threadIdx.x >> 6, lane = threadIdx.x & 63;
    int n = blockIdx.x * 2 + wave;
    int c0 = lane << 1;  // channels c0, c0+1 ; head = lane>>4 (16-lane groups)
    float wv0[EDD], wv1[EDD];
    #pragma unroll
    for (int d = 0; d < EDD; d++) {
        wv0[d] = LD<F32>(We, d * HIDD + c0);
        wv1[d] = LD<F32>(We, d * HIDD + c0 + 1);
    }
    float be0 = LD<F32>(be, c0), be1 = LD<F32>(be, c0 + 1);
    float at0 = LD<F32>(att, c0), at1 = LD<F32>(att, c0 + 1);
    unsigned int xru = *(const unsigned int*)(xr + (n << 7) + c0);
    float xr0 = __uint_as_float(xru << 16);
    float xr1 = __uint_as_float(xru & 0xffff0000u);
    int lo = off[n], hi = off[n + 1];
    float acc0 = 0.f, acc1 = 0.f, den = 0.f;
    if (lo < hi) {
        int src = esrc[lo];
        uint4 eu = ea8[lo];
        unsigned int xu = *(const unsigned int*)(xl + (src << 7) + c0);
        for (int i = lo; i < hi; i++) {
            int ip = (i + 1 < hi) ? i + 1 : i;
            int src_n = esrc[ip];                    // prefetch next edge
            uint4 eu_n = ea8[ip];
            unsigned int xu_n = *(const unsigned int*)(xl + (src_n << 7) + c0);
            float e0 = __uint_as_float(eu.x << 16), e1 = __uint_as_float(eu.x & 0xffff0000u);
            float e2 = __uint_as_float(eu.y << 16), e3 = __uint_as_float(eu.y & 0xffff0000u);
            float e4 = __uint_as_float(eu.z << 16), e5 = __uint_as_float(eu.z & 0xffff0000u);
            float e6 = __uint_as_float(eu.w << 16), e7 = __uint_as_float(eu.w & 0xffff0000u);
            float ee0 = be0 + e0 * wv0[0] + e1 * wv0[1] + e2 * wv0[2] + e3 * wv0[3]
                            + e4 * wv0[4] + e5 * wv0[5] + e6 * wv0[6] + e7 * wv0[7];
            float ee1 = be1 + e0 * wv1[0] + e1 * wv1[1] + e2 * wv1[2] + e3 * wv1[3]
                            + e4 * wv1[4] + e5 * wv1[5] + e6 * wv1[6] + e7 * wv1[7];
            float x0 = __uint_as_float(xu << 16);
            float x1 = __uint_as_float(xu & 0xffff0000u);
            float s0 = x0 + xr0 + ee0; s0 = (s0 >= 0.f) ? s0 : 0.2f * s0;
            float s1 = x1 + xr1 + ee1; s1 = (s1 >= 0.f) ? s1 : 0.2f * s1;
            float ls = s0 * at0 + s1 * at1;
            ls += __shfl_xor(ls, 1);
            ls += __shfl_xor(ls, 2);
            ls += __shfl_xor(ls, 4);
            ls += __shfl_xor(ls, 8);   // sum over 16-lane head group = 32 channels
            float ex = __expf(ls);
            acc0 += ex * x0; acc1 += ex * x1; den += ex;
            src = src_n; eu = eu_n; xu = xu_n;
        }
    }
    float inv = (den > 0.f) ? 1.0f / den : 0.f;
    float hv0 = fmaxf(acc0 * inv + LD<F32>(bo, c0), 0.f);
    float hv1 = fmaxf(acc1 * inv + LD<F32>(bo, c0 + 1), 0.f);
    unsigned int zu = *(const unsigned int*)(zb + (n << 7) + c0);
    float v0 = __uint_as_float(zu << 16) + hv0;
    float v1 = __uint_as_float(zu & 0xffff0000u) + hv1;
    float s = v0 + v1;
    #pragma unroll
    for (int m = 32; m; m >>= 1) s += __shfl_xor(s, m);
    float mu = s * (1.f / HIDD);
    float d0 = v0 - mu, d1 = v1 - mu;
    float s2 = d0 * d0 + d1 * d1;
    #pragma unroll
    for (int m = 32; m; m >>= 1) s2 += __shfl_xor(s2, m);
    float rs = rsqrtf(s2 * (1.f / HIDD) + 1e-5f);
    float o0 = d0 * rs * LD<F32>(g, c0) + LD<F32>(beta, c0);
    float o1 = d1 * rs * LD<F32>(g, c0 + 1) + LD<F32>(beta, c0 + 1);
    if constexpr (!LAST) {
        unsigned int pk = (unsigned int)f2bu(o0) | ((unsigned int)f2bu(o1) << 16);
        *(unsigned int*)(zb + (n << 7) + c0) = pk;
    } else {
        float po = o0 * LD<F32>(Wo, c0) + o1 * LD<F32>(Wo, c0 + 1);
        #pragma unroll
        for (int m = 32; m; m >>= 1) po += __shfl_xor(po, m);
        if (lane == 0) {
            float r = po + LD<F32>(bout, 0);
            if constexpr (F32) ((float*)out)[n] = r;
            else               ((bf16*)out)[n] = __float2bfloat16(r);
        }
    }
}
__global__ void k_gat(const int* cnt, const int* off, const int* esrc, const uint4* ea8,
                      const void* We, const void* be, const void* att,
                      const bf16* xl, const bf16* xr, const void* bo, bf16* zb,
                      const void* g, const void* beta) {
    if (is_f32(cnt)) gat_impl<true, false>(off, esrc, ea8, We, be, att, xl, xr, bo, zb, g, beta, nullptr, nullptr, nullptr);
    else             gat_impl<false, false>(off, esrc, ea8, We, be, att, xl, xr, bo, zb, g, beta, nullptr, nullptr, nullptr);
}
__global__ void k_gat_last(const int* cnt, const int* off, const int* esrc, const uint4* ea8,
                           const void* We, const void* be, const void* att,
                           const bf16* xl, const bf16* xr, const void* bo, bf16* zb,
                           const void* g, const void* beta,
                           const void* Wo, const void* bout, void* out) {
    if (is_f32(cnt)) gat_impl<true, true>(off, esrc, ea8, We, be, att, xl, xr, bo, zb, g, beta, Wo, bout, out);
    else             gat_impl<false, true>(off, esrc, ea8, We, be, att, xl, xr, bo, zb, g, beta, Wo, bout, out);
}

extern "C" void kernel_launch(void* const* d_in, const int* in_sizes, int n_in,
                              void* d_out, int out_size, void* d_ws, size_t ws_size,
                              hipStream_t stream) {
    const void* x        = d_in[0];
    const int*  node_idx = (const int*)d_in[1];
    const int*  ei       = (const int*)d_in[2];
    const void* ea       = d_in[3];
    const void* emb      = d_in[4];
    const void* W_in     = d_in[5];
    const void* b_in     = d_in[6];
    const void* Wl1 = d_in[7];  const void* bl1 = d_in[8];
    const void* Wr1 = d_in[9];  const void* br1 = d_in[10];
    const void* We1 = d_in[11]; const void* be1 = d_in[12];
    const void* att1 = d_in[13]; const void* bo1 = d_in[14];
    const void* Wl2 = d_in[15]; const void* bl2 = d_in[16];
    const void* Wr2 = d_in[17]; const void* br2 = d_in[18];
    const void* We2 = d_in[19]; const void* be2 = d_in[20];
    const void* att2 = d_in[21]; const void* bo2 = d_in[22];
    const void* g1 = d_in[23]; const void* beta1 = d_in[24];
    const void* g2 = d_in[25]; const void* beta2 = d_in[26];
    const void* W_out = d_in[27]; const void* b_out = d_in[28];

    // workspace (~54 MB), 16B-aligned sections:
    int*   cnt  = (int*)d_ws;                              // 64 ints
    uint4* ea8  = (uint4*)((char*)d_ws + 256);             // NE uint4
    bf16*  zb   = (bf16*)(ea8 + NE);                       // NN*HIDD
    bf16*  xl   = zb + NN * HIDD;                          // NN*HIDD
    bf16*  xr   = xl + NN * HIDD;                          // NN*HIDD
    bf16*  wbT  = xr + NN * HIDD;                          // 2*256*128
    float* bias = (float*)(wbT + 2 * 256 * HIDD);          // 2*256
    int*   off  = (int*)(bias + 2 * 256);                  // NN+1
    int*   deg  = off + NN + 1;                            // NN
    int*   rank = deg + NN;                                // NE
    int*   esrc = rank + NE;                               // NE
    int*   bsum = esrc + NE;                               // 256

    int nhalf = in_sizes[0] < 65536 ? in_sizes[0] : 65536;
    k_init0<<<(NN + 255) / 256, 256, 0, stream>>>(cnt, deg);
    k_detect<<<64, 256, 0, stream>>>((const unsigned short*)x, nhalf, cnt);
    k_build_z<<<NN, 128, 0, stream>>>(cnt, x, node_idx, emb, W_in, b_in, zb);

    // CSR by dst (shared by both layers)
    k_hist<<<(NE + 255) / 256, 256, 0, stream>>>(ei, deg, rank);
    k_scan1<<<NB_SCAN, 256, 0, stream>>>(deg, off, bsum);
    k_scan2<<<1, 256, 0, stream>>>(bsum);
    k_scan3<<<NB_SCAN, 256, 0, stream>>>(off, bsum);
    k_fill<<<(NE + 255) / 256, 256, 0, stream>>>(cnt, ei, off, rank, esrc, ea8, ea);

    k_prepw<<<512, HIDD, 0, stream>>>(cnt, Wl1, bl1, Wr1, br1, Wl2, bl2, Wr2, br2, wbT, bias);

    // ---- layer 1 ----
    k_projmm<<<NN / 16, 256, 0, stream>>>(zb, wbT, bias, xl, xr);
    k_gat<<<NN / 2, 128, 0, stream>>>(cnt, off, esrc, ea8, We1, be1, att1, xl, xr, bo1, zb, g1, beta1);

    // ---- layer 2 ----
    k_projmm<<<NN / 16, 256, 0, stream>>>(zb, wbT + 256 * HIDD, bias + 256, xl, xr);
    k_gat_last<<<NN / 2, 128, 0, stream>>>(cnt, off, esrc, ea8, We2, be2, att2, xl, xr, bo2, zb,
                                           g2, beta2, W_out, b_out, d_out);
}

// Round 10
// 438.363 us; speedup vs baseline: 3.6324x; 1.0548x over previous
//
#include <hip/hip_runtime.h>
#include <hip/hip_bf16.h>

#define NN 50000
#define NE 600000
#define IND 16
#define EDD 8
#define HIDD 128
#define NH 4
#define CC 32
#define EMBD 64
#define FEATD 64
#define NB_SCAN ((NN + 255) / 256)  // 196

typedef __hip_bfloat16 bf16;
typedef __attribute__((ext_vector_type(8))) short bshort8;
typedef __attribute__((ext_vector_type(4))) float floatx4;

__device__ __forceinline__ float b2f(bf16 v) { return __bfloat162float(v); }

// round-to-nearest-even f32 -> bf16 bits
__device__ __forceinline__ unsigned short f2bu(float f) {
    unsigned int u = __float_as_uint(f);
    u += 0x7fffu + ((u >> 16) & 1u);
    return (unsigned short)(u >> 16);
}

template <bool F32>
__device__ __forceinline__ float LD(const void* p, long long i) {
    if constexpr (F32) return ((const float*)p)[i];
    else return __bfloat162float(((const bf16*)p)[i]);
}

// ---- zero cnt + deg in one launch
__global__ void k_init0(int* __restrict__ cnt, int* __restrict__ deg) {
    int i = blockIdx.x * blockDim.x + threadIdx.x;
    if (i == 0) *cnt = 0;
    if (i < NN) deg[i] = 0;
}

// ---- dtype detector (fp32 misread as bf16 shows ~2^-8 rate of exp==0xFF halfwords)
__global__ void k_detect(const unsigned short* __restrict__ x, int nhalf, int* __restrict__ cnt) {
    __shared__ int c;
    if (threadIdx.x == 0) c = 0;
    __syncthreads();
    int i = blockIdx.x * blockDim.x + threadIdx.x;
    int hits = 0;
    for (; i < nhalf; i += gridDim.x * blockDim.x)
        if ((x[i] & 0x7F80u) == 0x7F80u) hits++;
    if (hits) atomicAdd(&c, hits);
    __syncthreads();
    if (threadIdx.x == 0 && c) atomicAdd(cnt, c);
}

__device__ __forceinline__ bool is_f32(const int* cnt) { return *cnt > 8; }

// ---- CSR: histogram also records each edge's rank within its dst bucket
__global__ void k_hist(const int* __restrict__ ei, int* __restrict__ deg, int* __restrict__ rank) {
    int e = blockIdx.x * blockDim.x + threadIdx.x;
    if (e < NE) rank[e] = atomicAdd(&deg[ei[NE + e]], 1);
}

// level 1: per-tile exclusive scan (local) + block totals
__global__ void k_scan1(const int* __restrict__ deg, int* __restrict__ off,
                        int* __restrict__ bsum) {
    __shared__ int tile[256];
    int t = threadIdx.x;
    int gid = blockIdx.x * 256 + t;
    int v = (gid < NN) ? deg[gid] : 0;
    tile[t] = v;
    __syncthreads();
    #pragma unroll
    for (int o = 1; o < 256; o <<= 1) {
        int u = (t >= o) ? tile[t - o] : 0;
        __syncthreads();
        tile[t] += u;
        __syncthreads();
    }
    if (gid < NN) off[gid] = tile[t] - v;
    if (t == 255) bsum[blockIdx.x] = tile[255];
}
// level 2: single block scans the 196 block sums -> exclusive
__global__ void k_scan2(int* __restrict__ bsum) {
    __shared__ int tile[256];
    int t = threadIdx.x;
    int v = (t < NB_SCAN) ? bsum[t] : 0;
    tile[t] = v;
    __syncthreads();
    #pragma unroll
    for (int o = 1; o < 256; o <<= 1) {
        int u = (t >= o) ? tile[t - o] : 0;
        __syncthreads();
        tile[t] += u;
        __syncthreads();
    }
    if (t < NB_SCAN) bsum[t] = tile[t] - v;
}
// level 3: add block offset; off[NN]=NE
__global__ void k_scan3(int* __restrict__ off, const int* __restrict__ bsum) {
    int gid = blockIdx.x * 256 + threadIdx.x;
    if (gid < NN) off[gid] += bsum[blockIdx.x];
    if (gid == 0) off[NN] = NE;
}

// slot = off[dst] + rank[e] -> esrc + packed bf16 edge_attr, CSR-sorted. No atomics.
template <bool F32>
__device__ void fill_impl(const int* __restrict__ ei, const int* __restrict__ off,
                          const int* __restrict__ rank, int* __restrict__ esrc,
                          uint4* __restrict__ ea8, const void* ea) {
    int e = blockIdx.x * blockDim.x + threadIdx.x;
    if (e >= NE) return;
    int slot = off[ei[NE + e]] + rank[e];
    esrc[slot] = ei[e];
    unsigned int w[4];
    #pragma unroll
    for (int d = 0; d < 4; d++) {
        unsigned int lo = f2bu(LD<F32>(ea, (long long)e * EDD + 2 * d));
        unsigned int hi = f2bu(LD<F32>(ea, (long long)e * EDD + 2 * d + 1));
        w[d] = lo | (hi << 16);
    }
    uint4 v; v.x = w[0]; v.y = w[1]; v.z = w[2]; v.w = w[3];
    ea8[slot] = v;
}
__global__ void k_fill(const int* cnt, const int* ei, const int* off, const int* rank,
                       int* esrc, uint4* ea8, const void* ea) {
    if (is_f32(cnt)) fill_impl<true>(ei, off, rank, esrc, ea8, ea);
    else             fill_impl<false>(ei, off, rank, esrc, ea8, ea);
}

// ---- zb[n] = bf16(concat(relu(x[n] @ W_in + b_in), emb[node_idx[n]]))
template <bool F32>
__device__ void build_z_impl(const void* x, const int* __restrict__ node_idx, const void* emb,
                             const void* W_in, const void* b_in, bf16* __restrict__ zb) {
    int n = blockIdx.x, t = threadIdx.x;  // 128
    float val;
    if (t < FEATD) {
        float acc = LD<F32>(b_in, t);
        #pragma unroll
        for (int k = 0; k < IND; k++)
            acc += LD<F32>(x, (long long)n * IND + k) * LD<F32>(W_in, k * FEATD + t);
        val = fmaxf(acc, 0.f);
    } else {
        val = LD<F32>(emb, (long long)node_idx[n] * EMBD + (t - FEATD));
    }
    zb[n * HIDD + t] = __float2bfloat16(val);
}
__global__ void k_build_z(const int* cnt, const void* x, const int* node_idx, const void* emb,
                          const void* W_in, const void* b_in, bf16* zb) {
    if (is_f32(cnt)) build_z_impl<true>(x, node_idx, emb, W_in, b_in, zb);
    else             build_z_impl<false>(x, node_idx, emb, W_in, b_in, zb);
}

// ---- weight prep, BOTH layers in one launch: wbT[layer][n][k], bias[layer][n]
template <bool F32>
__device__ void prepw_impl(const void* Wl1, const void* bl1, const void* Wr1, const void* br1,
                           const void* Wl2, const void* bl2, const void* Wr2, const void* br2,
                           bf16* __restrict__ wbT, float* __restrict__ bias) {
    int layer = blockIdx.x >> 8;
    int n = blockIdx.x & 255;
    int k = threadIdx.x;  // 128
    const void* W = layer ? (n < HIDD ? Wl2 : Wr2) : (n < HIDD ? Wl1 : Wr1);
    const void* b = layer ? (n < HIDD ? bl2 : br2) : (n < HIDD ? bl1 : br1);
    int nn = n & (HIDD - 1);
    wbT[(layer * 256 + n) * HIDD + k] = __float2bfloat16(LD<F32>(W, k * HIDD + nn));
    if (k == 0) bias[layer * 256 + n] = LD<F32>(b, nn);
}
__global__ void k_prepw(const int* cnt,
                        const void* Wl1, const void* bl1, const void* Wr1, const void* br1,
                        const void* Wl2, const void* bl2, const void* Wr2, const void* br2,
                        bf16* wbT, float* bias) {
    if (is_f32(cnt)) prepw_impl<true>(Wl1, bl1, Wr1, br1, Wl2, bl2, Wr2, br2, wbT, bias);
    else             prepw_impl<false>(Wl1, bl1, Wr1, br1, Wl2, bl2, Wr2, br2, wbT, bias);
}

// ---- MFMA projection: [xl|xr] = zb @ wbT^T + bias. 64-node M-tile per block;
// all 16 B-fragments held in registers across the 4 M-subtiles.
__global__ __launch_bounds__(256) void k_projmm(const bf16* __restrict__ zb,
                                                const bf16* __restrict__ wbT,
                                                const float* __restrict__ bias,
                                                bf16* __restrict__ xl, bf16* __restrict__ xr) {
    int wave = threadIdx.x >> 6, lane = threadIdx.x & 63;
    int m0 = blockIdx.x * 64;
    int n0 = wave * 64;
    int l15 = lane & 15, q = lane >> 4;
    bshort8 bfr[4][4];  // [j][ks]
    #pragma unroll
    for (int j = 0; j < 4; j++)
        #pragma unroll
        for (int s = 0; s < 4; s++)
            bfr[j][s] = *(const bshort8*)(wbT + ((n0 + j * 16 + l15) << 7) + s * 32 + q * 8);
    float bv[4];
    #pragma unroll
    for (int j = 0; j < 4; j++) bv[j] = bias[n0 + j * 16 + l15];
    #pragma unroll
    for (int mi = 0; mi < 4; mi++) {
        const bf16* arow = zb + ((long long)(m0 + mi * 16 + l15) << 7) + q * 8;
        floatx4 acc0 = {0.f, 0.f, 0.f, 0.f}, acc1 = acc0, acc2 = acc0, acc3 = acc0;
        #pragma unroll
        for (int s = 0; s < 4; s++) {
            bshort8 a = *(const bshort8*)(arow + s * 32);
            acc0 = __builtin_amdgcn_mfma_f32_16x16x32_bf16(a, bfr[0][s], acc0, 0, 0, 0);
            acc1 = __builtin_amdgcn_mfma_f32_16x16x32_bf16(a, bfr[1][s], acc1, 0, 0, 0);
            acc2 = __builtin_amdgcn_mfma_f32_16x16x32_bf16(a, bfr[2][s], acc2, 0, 0, 0);
            acc3 = __builtin_amdgcn_mfma_f32_16x16x32_bf16(a, bfr[3][s], acc3, 0, 0, 0);
        }
        floatx4 accs[4] = {acc0, acc1, acc2, acc3};
        #pragma unroll
        for (int j = 0; j < 4; j++) {
            int colg = n0 + j * 16 + l15;
            bf16* dst = (colg < HIDD) ? (xl + colg) : (xr + (colg - HIDD));
            #pragma unroll
            for (int r = 0; r < 4; r++) {
                int rowc = m0 + mi * 16 + q * 4 + r;
                if (rowc < NN) dst[(long long)rowc << 7] = __float2bfloat16(accs[j][r] + bv[j]);
            }
        }
    }
}

// ---- fused GAT layer: 1 wave/node (4 nodes per 256-thr block), 2 ch/lane,
// 2-edge ILP with pair-ahead prefetch, barrier-free LN. LAST fuses output head.
template <bool F32, bool LAST>
__device__ void gat_impl(const int* __restrict__ off, const int* __restrict__ esrc,
                         const uint4* __restrict__ ea8,
                         const void* We, const void* be, const void* att,
                         const bf16* __restrict__ xl, const bf16* __restrict__ xr,
                         const void* bo, bf16* __restrict__ zb,
                         const void* g, const void* beta,
                         const void* Wo, const void* bout, void* out) {
    int wave = threadIdx.x >> 6, lane = threadIdx.x & 63;
    int n = blockIdx.x * 4 + wave;
    int c0 = lane << 1;  // channels c0, c0+1 ; head = lane>>4 (16-lane groups)
    float wv0[EDD], wv1[EDD];
    #pragma unroll
    for (int d = 0; d < EDD; d++) {
        wv0[d] = LD<F32>(We, d * HIDD + c0);
        wv1[d] = LD<F32>(We, d * HIDD + c0 + 1);
    }
    float be0 = LD<F32>(be, c0), be1 = LD<F32>(be, c0 + 1);
    float at0 = LD<F32>(att, c0), at1 = LD<F32>(att, c0 + 1);
    unsigned int xru = *(const unsigned int*)(xr + ((long long)n << 7) + c0);
    float xr0 = __uint_as_float(xru << 16);
    float xr1 = __uint_as_float(xru & 0xffff0000u);
    int lo = off[n], hi = off[n + 1];
    float acc0 = 0.f, acc1 = 0.f, den = 0.f;
    float acc0b = 0.f, acc1b = 0.f, denb = 0.f;
    if (lo < hi) {
        int iA = lo, iB = (lo + 1 < hi) ? lo + 1 : lo;
        int srcA = esrc[iA];              uint4 euA = ea8[iA];
        int srcB = esrc[iB];              uint4 euB = ea8[iB];
        unsigned int xuA = *(const unsigned int*)(xl + ((long long)srcA << 7) + c0);
        unsigned int xuB = *(const unsigned int*)(xl + ((long long)srcB << 7) + c0);
        for (int i = lo; i < hi; i += 2) {
            // prefetch next pair (clamped)
            int j0 = (i + 2 < hi) ? i + 2 : hi - 1;
            int j1 = (i + 3 < hi) ? i + 3 : hi - 1;
            int srcA_n = esrc[j0];        uint4 euA_n = ea8[j0];
            int srcB_n = esrc[j1];        uint4 euB_n = ea8[j1];
            unsigned int xuA_n = *(const unsigned int*)(xl + ((long long)srcA_n << 7) + c0);
            unsigned int xuB_n = *(const unsigned int*)(xl + ((long long)srcB_n << 7) + c0);
            // ---- edge A (always valid)
            {
                float e0 = __uint_as_float(euA.x << 16), e1 = __uint_as_float(euA.x & 0xffff0000u);
                float e2 = __uint_as_float(euA.y << 16), e3 = __uint_as_float(euA.y & 0xffff0000u);
                float e4 = __uint_as_float(euA.z << 16), e5 = __uint_as_float(euA.z & 0xffff0000u);
                float e6 = __uint_as_float(euA.w << 16), e7 = __uint_as_float(euA.w & 0xffff0000u);
                float ee0 = be0 + e0 * wv0[0] + e1 * wv0[1] + e2 * wv0[2] + e3 * wv0[3]
                                + e4 * wv0[4] + e5 * wv0[5] + e6 * wv0[6] + e7 * wv0[7];
                float ee1 = be1 + e0 * wv1[0] + e1 * wv1[1] + e2 * wv1[2] + e3 * wv1[3]
                                + e4 * wv1[4] + e5 * wv1[5] + e6 * wv1[6] + e7 * wv1[7];
                float x0 = __uint_as_float(xuA << 16);
                float x1 = __uint_as_float(xuA & 0xffff0000u);
                float s0 = x0 + xr0 + ee0; s0 = (s0 >= 0.f) ? s0 : 0.2f * s0;
                float s1 = x1 + xr1 + ee1; s1 = (s1 >= 0.f) ? s1 : 0.2f * s1;
                float ls = s0 * at0 + s1 * at1;
                ls += __shfl_xor(ls, 1);
                ls += __shfl_xor(ls, 2);
                ls += __shfl_xor(ls, 4);
                ls += __shfl_xor(ls, 8);
                float ex = __expf(ls);
                acc0 += ex * x0; acc1 += ex * x1; den += ex;
            }
            // ---- edge B (masked if odd tail)
            {
                float valid = (i + 1 < hi) ? 1.f : 0.f;
                float e0 = __uint_as_float(euB.x << 16), e1 = __uint_as_float(euB.x & 0xffff0000u);
                float e2 = __uint_as_float(euB.y << 16), e3 = __uint_as_float(euB.y & 0xffff0000u);
                float e4 = __uint_as_float(euB.z << 16), e5 = __uint_as_float(euB.z & 0xffff0000u);
                float e6 = __uint_as_float(euB.w << 16), e7 = __uint_as_float(euB.w & 0xffff0000u);
                float ee0 = be0 + e0 * wv0[0] + e1 * wv0[1] + e2 * wv0[2] + e3 * wv0[3]
                                + e4 * wv0[4] + e5 * wv0[5] + e6 * wv0[6] + e7 * wv0[7];
                float ee1 = be1 + e0 * wv1[0] + e1 * wv1[1] + e2 * wv1[2] + e3 * wv1[3]
                                + e4 * wv1[4] + e5 * wv1[5] + e6 * wv1[6] + e7 * wv1[7];
                float x0 = __uint_as_float(xuB << 16);
                float x1 = __uint_as_float(xuB & 0xffff0000u);
                float s0 = x0 + xr0 + ee0; s0 = (s0 >= 0.f) ? s0 : 0.2f * s0;
                float s1 = x1 + xr1 + ee1; s1 = (s1 >= 0.f) ? s1 : 0.2f * s1;
                float ls = s0 * at0 + s1 * at1;
                ls += __shfl_xor(ls, 1);
                ls += __shfl_xor(ls, 2);
                ls += __shfl_xor(ls, 4);
                ls += __shfl_xor(ls, 8);
                float ex = __expf(ls) * valid;
                acc0b += ex * x0; acc1b += ex * x1; denb += ex;
            }
            srcA = srcA_n; euA = euA_n; xuA = xuA_n;
            srcB = srcB_n; euB = euB_n; xuB = xuB_n;
        }
        acc0 += acc0b; acc1 += acc1b; den += denb;
    }
    float inv = (den > 0.f) ? 1.0f / den : 0.f;
    float hv0 = fmaxf(acc0 * inv + LD<F32>(bo, c0), 0.f);
    float hv1 = fmaxf(acc1 * inv + LD<F32>(bo, c0 + 1), 0.f);
    unsigned int zu = *(const unsigned int*)(zb + ((long long)n << 7) + c0);
    float v0 = __uint_as_float(zu << 16) + hv0;
    float v1 = __uint_as_float(zu & 0xffff0000u) + hv1;
    float s = v0 + v1;
    #pragma unroll
    for (int m = 32; m; m >>= 1) s += __shfl_xor(s, m);
    float mu = s * (1.f / HIDD);
    float d0 = v0 - mu, d1 = v1 - mu;
    float s2 = d0 * d0 + d1 * d1;
    #pragma unroll
    for (int m = 32; m; m >>= 1) s2 += __shfl_xor(s2, m);
    float rs = rsqrtf(s2 * (1.f / HIDD) + 1e-5f);
    float o0 = d0 * rs * LD<F32>(g, c0) + LD<F32>(beta, c0);
    float o1 = d1 * rs * LD<F32>(g, c0 + 1) + LD<F32>(beta, c0 + 1);
    if constexpr (!LAST) {
        unsigned int pk = (unsigned int)f2bu(o0) | ((unsigned int)f2bu(o1) << 16);
        *(unsigned int*)(zb + ((long long)n << 7) + c0) = pk;
    } else {
        float po = o0 * LD<F32>(Wo, c0) + o1 * LD<F32>(Wo, c0 + 1);
        #pragma unroll
        for (int m = 32; m; m >>= 1) po += __shfl_xor(po, m);
        if (lane == 0) {
            float r = po + LD<F32>(bout, 0);
            if constexpr (F32) ((float*)out)[n] = r;
            else               ((bf16*)out)[n] = __float2bfloat16(r);
        }
    }
}
__global__ void k_gat(const int* cnt, const int* off, const int* esrc, const uint4* ea8,
                      const void* We, const void* be, const void* att,
                      const bf16* xl, const bf16* xr, const void* bo, bf16* zb,
                      const void* g, const void* beta) {
    if (is_f32(cnt)) gat_impl<true, false>(off, esrc, ea8, We, be, att, xl, xr, bo, zb, g, beta, nullptr, nullptr, nullptr);
    else             gat_impl<false, false>(off, esrc, ea8, We, be, att, xl, xr, bo, zb, g, beta, nullptr, nullptr, nullptr);
}
__global__ void k_gat_last(const int* cnt, const int* off, const int* esrc, const uint4* ea8,
                           const void* We, const void* be, const void* att,
                           const bf16* xl, const bf16* xr, const void* bo, bf16* zb,
                           const void* g, const void* beta,
                           const void* Wo, const void* bout, void* out) {
    if (is_f32(cnt)) gat_impl<true, true>(off, esrc, ea8, We, be, att, xl, xr, bo, zb, g, beta, Wo, bout, out);
    else             gat_impl<false, true>(off, esrc, ea8, We, be, att, xl, xr, bo, zb, g, beta, Wo, bout, out);
}

extern "C" void kernel_launch(void* const* d_in, const int* in_sizes, int n_in,
                              void* d_out, int out_size, void* d_ws, size_t ws_size,
                              hipStream_t stream) {
    const void* x        = d_in[0];
    const int*  node_idx = (const int*)d_in[1];
    const int*  ei       = (const int*)d_in[2];
    const void* ea       = d_in[3];
    const void* emb      = d_in[4];
    const void* W_in     = d_in[5];
    const void* b_in     = d_in[6];
    const void* Wl1 = d_in[7];  const void* bl1 = d_in[8];
    const void* Wr1 = d_in[9];  const void* br1 = d_in[10];
    const void* We1 = d_in[11]; const void* be1 = d_in[12];
    const void* att1 = d_in[13]; const void* bo1 = d_in[14];
    const void* Wl2 = d_in[15]; const void* bl2 = d_in[16];
    const void* Wr2 = d_in[17]; const void* br2 = d_in[18];
    const void* We2 = d_in[19]; const void* be2 = d_in[20];
    const void* att2 = d_in[21]; const void* bo2 = d_in[22];
    const void* g1 = d_in[23]; const void* beta1 = d_in[24];
    const void* g2 = d_in[25]; const void* beta2 = d_in[26];
    const void* W_out = d_in[27]; const void* b_out = d_in[28];

    // workspace (~54 MB), 16B-aligned sections:
    int*   cnt  = (int*)d_ws;                              // 64 ints
    uint4* ea8  = (uint4*)((char*)d_ws + 256);             // NE uint4
    bf16*  zb   = (bf16*)(ea8 + NE);                       // NN*HIDD
    bf16*  xl   = zb + NN * HIDD;                          // NN*HIDD
    bf16*  xr   = xl + NN * HIDD;                          // NN*HIDD
    bf16*  wbT  = xr + NN * HIDD;                          // 2*256*128
    float* bias = (float*)(wbT + 2 * 256 * HIDD);          // 2*256
    int*   off  = (int*)(bias + 2 * 256);                  // NN+1
    int*   deg  = off + NN + 1;                            // NN
    int*   rank = deg + NN;                                // NE
    int*   esrc = rank + NE;                               // NE
    int*   bsum = esrc + NE;                               // 256

    int nhalf = in_sizes[0] < 65536 ? in_sizes[0] : 65536;
    k_init0<<<(NN + 255) / 256, 256, 0, stream>>>(cnt, deg);
    k_detect<<<64, 256, 0, stream>>>((const unsigned short*)x, nhalf, cnt);
    k_build_z<<<NN, 128, 0, stream>>>(cnt, x, node_idx, emb, W_in, b_in, zb);

    // CSR by dst (shared by both layers)
    k_hist<<<(NE + 255) / 256, 256, 0, stream>>>(ei, deg, rank);
    k_scan1<<<NB_SCAN, 256, 0, stream>>>(deg, off, bsum);
    k_scan2<<<1, 256, 0, stream>>>(bsum);
    k_scan3<<<NB_SCAN, 256, 0, stream>>>(off, bsum);
    k_fill<<<(NE + 255) / 256, 256, 0, stream>>>(cnt, ei, off, rank, esrc, ea8, ea);

    k_prepw<<<512, HIDD, 0, stream>>>(cnt, Wl1, bl1, Wr1, br1, Wl2, bl2, Wr2, br2, wbT, bias);

    // ---- layer 1 ----
    k_projmm<<<(NN + 63) / 64, 256, 0, stream>>>(zb, wbT, bias, xl, xr);
    k_gat<<<NN / 4, 256, 0, stream>>>(cnt, off, esrc, ea8, We1, be1, att1, xl, xr, bo1, zb, g1, beta1);

    // ---- layer 2 ----
    k_projmm<<<(NN + 63) / 64, 256, 0, stream>>>(zb, wbT + 256 * HIDD, bias + 256, xl, xr);
    k_gat_last<<<NN / 4, 256, 0, stream>>>(cnt, off, esrc, ea8, We2, be2, att2, xl, xr, bo2, zb,
                                           g2, beta2, W_out, b_out, d_out);
}

// Round 11
// 422.809 us; speedup vs baseline: 3.7660x; 1.0368x over previous
//
#include <hip/hip_runtime.h>
#include <hip/hip_bf16.h>

#define NN 50000
#define NE 600000
#define IND 16
#define EDD 8
#define HIDD 128
#define NH 4
#define CC 32
#define EMBD 64
#define FEATD 64
#define NB_SCAN ((NN + 255) / 256)  // 196

typedef __hip_bfloat16 bf16;
typedef __attribute__((ext_vector_type(8))) short bshort8;
typedef __attribute__((ext_vector_type(4))) float floatx4;

__device__ __forceinline__ float b2f(bf16 v) { return __bfloat162float(v); }

// round-to-nearest-even f32 -> bf16 bits
__device__ __forceinline__ unsigned short f2bu(float f) {
    unsigned int u = __float_as_uint(f);
    u += 0x7fffu + ((u >> 16) & 1u);
    return (unsigned short)(u >> 16);
}

template <bool F32>
__device__ __forceinline__ float LD(const void* p, long long i) {
    if constexpr (F32) return ((const float*)p)[i];
    else return __bfloat162float(((const bf16*)p)[i]);
}

// ---- zero cnt + deg in one launch
__global__ void k_init0(int* __restrict__ cnt, int* __restrict__ deg) {
    int i = blockIdx.x * blockDim.x + threadIdx.x;
    if (i == 0) *cnt = 0;
    if (i < NN) deg[i] = 0;
}

// ---- dtype detector (fp32 misread as bf16 shows ~2^-8 rate of exp==0xFF halfwords)
__global__ void k_detect(const unsigned short* __restrict__ x, int nhalf, int* __restrict__ cnt) {
    __shared__ int c;
    if (threadIdx.x == 0) c = 0;
    __syncthreads();
    int i = blockIdx.x * blockDim.x + threadIdx.x;
    int hits = 0;
    for (; i < nhalf; i += gridDim.x * blockDim.x)
        if ((x[i] & 0x7F80u) == 0x7F80u) hits++;
    if (hits) atomicAdd(&c, hits);
    __syncthreads();
    if (threadIdx.x == 0 && c) atomicAdd(cnt, c);
}

__device__ __forceinline__ bool is_f32(const int* cnt) { return *cnt > 8; }

// ---- CSR: histogram also records each edge's rank within its dst bucket
__global__ void k_hist(const int* __restrict__ ei, int* __restrict__ deg, int* __restrict__ rank) {
    int e = blockIdx.x * blockDim.x + threadIdx.x;
    if (e < NE) rank[e] = atomicAdd(&deg[ei[NE + e]], 1);
}

// level 1: per-tile exclusive scan (local) + block totals
__global__ void k_scan1(const int* __restrict__ deg, int* __restrict__ off,
                        int* __restrict__ bsum) {
    __shared__ int tile[256];
    int t = threadIdx.x;
    int gid = blockIdx.x * 256 + t;
    int v = (gid < NN) ? deg[gid] : 0;
    tile[t] = v;
    __syncthreads();
    #pragma unroll
    for (int o = 1; o < 256; o <<= 1) {
        int u = (t >= o) ? tile[t - o] : 0;
        __syncthreads();
        tile[t] += u;
        __syncthreads();
    }
    if (gid < NN) off[gid] = tile[t] - v;
    if (t == 255) bsum[blockIdx.x] = tile[255];
}
// level 2: single block scans the 196 block sums -> exclusive
__global__ void k_scan2(int* __restrict__ bsum) {
    __shared__ int tile[256];
    int t = threadIdx.x;
    int v = (t < NB_SCAN) ? bsum[t] : 0;
    tile[t] = v;
    __syncthreads();
    #pragma unroll
    for (int o = 1; o < 256; o <<= 1) {
        int u = (t >= o) ? tile[t - o] : 0;
        __syncthreads();
        tile[t] += u;
        __syncthreads();
    }
    if (t < NB_SCAN) bsum[t] = tile[t] - v;
}
// level 3: add block offset; off[NN]=NE
__global__ void k_scan3(int* __restrict__ off, const int* __restrict__ bsum) {
    int gid = blockIdx.x * 256 + threadIdx.x;
    if (gid < NN) off[gid] += bsum[blockIdx.x];
    if (gid == 0) off[NN] = NE;
}

// slot = off[dst] + rank[e] -> esrc + packed bf16 edge_attr, CSR-sorted. No atomics.
template <bool F32>
__device__ void fill_impl(const int* __restrict__ ei, const int* __restrict__ off,
                          const int* __restrict__ rank, int* __restrict__ esrc,
                          uint4* __restrict__ ea8, const void* ea) {
    int e = blockIdx.x * blockDim.x + threadIdx.x;
    if (e >= NE) return;
    int slot = off[ei[NE + e]] + rank[e];
    esrc[slot] = ei[e];
    unsigned int w[4];
    #pragma unroll
    for (int d = 0; d < 4; d++) {
        unsigned int lo = f2bu(LD<F32>(ea, (long long)e * EDD + 2 * d));
        unsigned int hi = f2bu(LD<F32>(ea, (long long)e * EDD + 2 * d + 1));
        w[d] = lo | (hi << 16);
    }
    uint4 v; v.x = w[0]; v.y = w[1]; v.z = w[2]; v.w = w[3];
    ea8[slot] = v;
}
__global__ void k_fill(const int* cnt, const int* ei, const int* off, const int* rank,
                       int* esrc, uint4* ea8, const void* ea) {
    if (is_f32(cnt)) fill_impl<true>(ei, off, rank, esrc, ea8, ea);
    else             fill_impl<false>(ei, off, rank, esrc, ea8, ea);
}

// ---- zb[n] = bf16(concat(relu(x[n] @ W_in + b_in), emb[node_idx[n]]))
template <bool F32>
__device__ void build_z_impl(const void* x, const int* __restrict__ node_idx, const void* emb,
                             const void* W_in, const void* b_in, bf16* __restrict__ zb) {
    int n = blockIdx.x, t = threadIdx.x;  // 128
    float val;
    if (t < FEATD) {
        float acc = LD<F32>(b_in, t);
        #pragma unroll
        for (int k = 0; k < IND; k++)
            acc += LD<F32>(x, (long long)n * IND + k) * LD<F32>(W_in, k * FEATD + t);
        val = fmaxf(acc, 0.f);
    } else {
        val = LD<F32>(emb, (long long)node_idx[n] * EMBD + (t - FEATD));
    }
    zb[n * HIDD + t] = __float2bfloat16(val);
}
__global__ void k_build_z(const int* cnt, const void* x, const int* node_idx, const void* emb,
                          const void* W_in, const void* b_in, bf16* zb) {
    if (is_f32(cnt)) build_z_impl<true>(x, node_idx, emb, W_in, b_in, zb);
    else             build_z_impl<false>(x, node_idx, emb, W_in, b_in, zb);
}

// ---- weight prep, BOTH layers in one launch: wbT[layer][n][k], bias[layer][n]
template <bool F32>
__device__ void prepw_impl(const void* Wl1, const void* bl1, const void* Wr1, const void* br1,
                           const void* Wl2, const void* bl2, const void* Wr2, const void* br2,
                           bf16* __restrict__ wbT, float* __restrict__ bias) {
    int layer = blockIdx.x >> 8;
    int n = blockIdx.x & 255;
    int k = threadIdx.x;  // 128
    const void* W = layer ? (n < HIDD ? Wl2 : Wr2) : (n < HIDD ? Wl1 : Wr1);
    const void* b = layer ? (n < HIDD ? bl2 : br2) : (n < HIDD ? bl1 : br1);
    int nn = n & (HIDD - 1);
    wbT[(layer * 256 + n) * HIDD + k] = __float2bfloat16(LD<F32>(W, k * HIDD + nn));
    if (k == 0) bias[layer * 256 + n] = LD<F32>(b, nn);
}
__global__ void k_prepw(const int* cnt,
                        const void* Wl1, const void* bl1, const void* Wr1, const void* br1,
                        const void* Wl2, const void* bl2, const void* Wr2, const void* br2,
                        bf16* wbT, float* bias) {
    if (is_f32(cnt)) prepw_impl<true>(Wl1, bl1, Wr1, br1, Wl2, bl2, Wr2, br2, wbT, bias);
    else             prepw_impl<false>(Wl1, bl1, Wr1, br1, Wl2, bl2, Wr2, br2, wbT, bias);
}

// ---- MFMA projection: [xl|xr] = zb @ wbT^T + bias. 64-node M-tile per block;
// all 16 B-fragments held in registers across the 4 M-subtiles.
__global__ __launch_bounds__(256) void k_projmm(const bf16* __restrict__ zb,
                                                const bf16* __restrict__ wbT,
                                                const float* __restrict__ bias,
                                                bf16* __restrict__ xl, bf16* __restrict__ xr) {
    int wave = threadIdx.x >> 6, lane = threadIdx.x & 63;
    int m0 = blockIdx.x * 64;
    int n0 = wave * 64;
    int l15 = lane & 15, q = lane >> 4;
    bshort8 bfr[4][4];  // [j][ks]
    #pragma unroll
    for (int j = 0; j < 4; j++)
        #pragma unroll
        for (int s = 0; s < 4; s++)
            bfr[j][s] = *(const bshort8*)(wbT + ((n0 + j * 16 + l15) << 7) + s * 32 + q * 8);
    float bv[4];
    #pragma unroll
    for (int j = 0; j < 4; j++) bv[j] = bias[n0 + j * 16 + l15];
    #pragma unroll
    for (int mi = 0; mi < 4; mi++) {
        const bf16* arow = zb + ((long long)(m0 + mi * 16 + l15) << 7) + q * 8;
        floatx4 acc0 = {0.f, 0.f, 0.f, 0.f}, acc1 = acc0, acc2 = acc0, acc3 = acc0;
        #pragma unroll
        for (int s = 0; s < 4; s++) {
            bshort8 a = *(const bshort8*)(arow + s * 32);
            acc0 = __builtin_amdgcn_mfma_f32_16x16x32_bf16(a, bfr[0][s], acc0, 0, 0, 0);
            acc1 = __builtin_amdgcn_mfma_f32_16x16x32_bf16(a, bfr[1][s], acc1, 0, 0, 0);
            acc2 = __builtin_amdgcn_mfma_f32_16x16x32_bf16(a, bfr[2][s], acc2, 0, 0, 0);
            acc3 = __builtin_amdgcn_mfma_f32_16x16x32_bf16(a, bfr[3][s], acc3, 0, 0, 0);
        }
        floatx4 accs[4] = {acc0, acc1, acc2, acc3};
        #pragma unroll
        for (int j = 0; j < 4; j++) {
            int colg = n0 + j * 16 + l15;
            bf16* dst = (colg < HIDD) ? (xl + colg) : (xr + (colg - HIDD));
            #pragma unroll
            for (int r = 0; r < 4; r++) {
                int rowc = m0 + mi * 16 + q * 4 + r;
                if (rowc < NN) dst[(long long)rowc << 7] = __float2bfloat16(accs[j][r] + bv[j]);
            }
        }
    }
}

// ---- fused GAT layer: 2 nodes per wave (one per 32-lane half), 4 ch/lane.
// Head = 8-lane group (3-shfl att reduce). ea unpack/loads/exp amortized over
// 2 edges per wave-instruction. Rotating prefetch. Barrier-free LN within
// half-wave (shfl_xor masks <=16 never cross the 32-lane boundary).
// LAST fuses the output head.
template <bool F32, bool LAST>
__device__ void gat_impl(const int* __restrict__ off, const int* __restrict__ esrc,
                         const uint4* __restrict__ ea8,
                         const void* We, const void* be, const void* att,
                         const bf16* __restrict__ xl, const bf16* __restrict__ xr,
                         const void* bo, bf16* __restrict__ zb,
                         const void* g, const void* beta,
                         const void* Wo, const void* bout, void* out) {
    int wave = threadIdx.x >> 6;
    int half = (threadIdx.x >> 5) & 1;
    int lane5 = threadIdx.x & 31;
    int n = blockIdx.x * 8 + wave * 2 + half;
    int c0 = lane5 << 2;  // 4 channels c0..c0+3 ; head = lane5>>3
    float wv[EDD][4], at[4], bev[4];
    #pragma unroll
    for (int d = 0; d < EDD; d++)
        #pragma unroll
        for (int j = 0; j < 4; j++) wv[d][j] = LD<F32>(We, d * HIDD + c0 + j);
    #pragma unroll
    for (int j = 0; j < 4; j++) {
        at[j] = LD<F32>(att, c0 + j);
        bev[j] = LD<F32>(be, c0 + j);
    }
    uint2 xru = *(const uint2*)(xr + ((long long)n << 7) + c0);
    float xrv[4];
    xrv[0] = __uint_as_float(xru.x << 16);
    xrv[1] = __uint_as_float(xru.x & 0xffff0000u);
    xrv[2] = __uint_as_float(xru.y << 16);
    xrv[3] = __uint_as_float(xru.y & 0xffff0000u);
    int lo = off[n], hi = off[n + 1];
    float acc[4] = {0.f, 0.f, 0.f, 0.f};
    float den = 0.f;
    if (lo < hi) {
        int src = esrc[lo];
        uint4 eu = ea8[lo];
        uint2 xu = *(const uint2*)(xl + ((long long)src << 7) + c0);
        for (int i = lo; i < hi; i++) {
            int ip = (i + 1 < hi) ? i + 1 : i;
            int src_n = esrc[ip];
            uint4 eu_n = ea8[ip];
            uint2 xu_n = *(const uint2*)(xl + ((long long)src_n << 7) + c0);
            float e[8];
            e[0] = __uint_as_float(eu.x << 16); e[1] = __uint_as_float(eu.x & 0xffff0000u);
            e[2] = __uint_as_float(eu.y << 16); e[3] = __uint_as_float(eu.y & 0xffff0000u);
            e[4] = __uint_as_float(eu.z << 16); e[5] = __uint_as_float(eu.z & 0xffff0000u);
            e[6] = __uint_as_float(eu.w << 16); e[7] = __uint_as_float(eu.w & 0xffff0000u);
            float xv[4];
            xv[0] = __uint_as_float(xu.x << 16);
            xv[1] = __uint_as_float(xu.x & 0xffff0000u);
            xv[2] = __uint_as_float(xu.y << 16);
            xv[3] = __uint_as_float(xu.y & 0xffff0000u);
            float ls = 0.f;
            #pragma unroll
            for (int j = 0; j < 4; j++) {
                float ee = bev[j];
                #pragma unroll
                for (int d = 0; d < EDD; d++) ee += e[d] * wv[d][j];
                float s = xv[j] + xrv[j] + ee;
                s = fmaxf(s, 0.2f * s);  // leakyrelu (slope<1)
                ls += s * at[j];
            }
            ls += __shfl_xor(ls, 1);
            ls += __shfl_xor(ls, 2);
            ls += __shfl_xor(ls, 4);   // 8-lane head group = 32 channels
            float ex = __expf(ls);
            #pragma unroll
            for (int j = 0; j < 4; j++) acc[j] += ex * xv[j];
            den += ex;
            src = src_n; eu = eu_n; xu = xu_n;
        }
    }
    float inv = (den > 0.f) ? 1.0f / den : 0.f;
    uint2 zu = *(const uint2*)(zb + ((long long)n << 7) + c0);
    float zv[4];
    zv[0] = __uint_as_float(zu.x << 16);
    zv[1] = __uint_as_float(zu.x & 0xffff0000u);
    zv[2] = __uint_as_float(zu.y << 16);
    zv[3] = __uint_as_float(zu.y & 0xffff0000u);
    float v[4];
    float s = 0.f;
    #pragma unroll
    for (int j = 0; j < 4; j++) {
        float hv = fmaxf(acc[j] * inv + LD<F32>(bo, c0 + j), 0.f);
        v[j] = zv[j] + hv;
        s += v[j];
    }
    #pragma unroll
    for (int m = 16; m; m >>= 1) s += __shfl_xor(s, m);  // 32-lane sum
    float mu = s * (1.f / HIDD);
    float s2 = 0.f;
    float dv[4];
    #pragma unroll
    for (int j = 0; j < 4; j++) { dv[j] = v[j] - mu; s2 += dv[j] * dv[j]; }
    #pragma unroll
    for (int m = 16; m; m >>= 1) s2 += __shfl_xor(s2, m);
    float rs = rsqrtf(s2 * (1.f / HIDD) + 1e-5f);
    float o[4];
    #pragma unroll
    for (int j = 0; j < 4; j++)
        o[j] = dv[j] * rs * LD<F32>(g, c0 + j) + LD<F32>(beta, c0 + j);
    if constexpr (!LAST) {
        uint2 pk;
        pk.x = (unsigned int)f2bu(o[0]) | ((unsigned int)f2bu(o[1]) << 16);
        pk.y = (unsigned int)f2bu(o[2]) | ((unsigned int)f2bu(o[3]) << 16);
        *(uint2*)(zb + ((long long)n << 7) + c0) = pk;
    } else {
        float po = 0.f;
        #pragma unroll
        for (int j = 0; j < 4; j++) po += o[j] * LD<F32>(Wo, c0 + j);
        #pragma unroll
        for (int m = 16; m; m >>= 1) po += __shfl_xor(po, m);
        if (lane5 == 0) {
            float r = po + LD<F32>(bout, 0);
            if constexpr (F32) ((float*)out)[n] = r;
            else               ((bf16*)out)[n] = __float2bfloat16(r);
        }
    }
}
__global__ void k_gat(const int* cnt, const int* off, const int* esrc, const uint4* ea8,
                      const void* We, const void* be, const void* att,
                      const bf16* xl, const bf16* xr, const void* bo, bf16* zb,
                      const void* g, const void* beta) {
    if (is_f32(cnt)) gat_impl<true, false>(off, esrc, ea8, We, be, att, xl, xr, bo, zb, g, beta, nullptr, nullptr, nullptr);
    else             gat_impl<false, false>(off, esrc, ea8, We, be, att, xl, xr, bo, zb, g, beta, nullptr, nullptr, nullptr);
}
__global__ void k_gat_last(const int* cnt, const int* off, const int* esrc, const uint4* ea8,
                           const void* We, const void* be, const void* att,
                           const bf16* xl, const bf16* xr, const void* bo, bf16* zb,
                           const void* g, const void* beta,
                           const void* Wo, const void* bout, void* out) {
    if (is_f32(cnt)) gat_impl<true, true>(off, esrc, ea8, We, be, att, xl, xr, bo, zb, g, beta, Wo, bout, out);
    else             gat_impl<false, true>(off, esrc, ea8, We, be, att, xl, xr, bo, zb, g, beta, Wo, bout, out);
}

extern "C" void kernel_launch(void* const* d_in, const int* in_sizes, int n_in,
                              void* d_out, int out_size, void* d_ws, size_t ws_size,
                              hipStream_t stream) {
    const void* x        = d_in[0];
    const int*  node_idx = (const int*)d_in[1];
    const int*  ei       = (const int*)d_in[2];
    const void* ea       = d_in[3];
    const void* emb      = d_in[4];
    const void* W_in     = d_in[5];
    const void* b_in     = d_in[6];
    const void* Wl1 = d_in[7];  const void* bl1 = d_in[8];
    const void* Wr1 = d_in[9];  const void* br1 = d_in[10];
    const void* We1 = d_in[11]; const void* be1 = d_in[12];
    const void* att1 = d_in[13]; const void* bo1 = d_in[14];
    const void* Wl2 = d_in[15]; const void* bl2 = d_in[16];
    const void* Wr2 = d_in[17]; const void* br2 = d_in[18];
    const void* We2 = d_in[19]; const void* be2 = d_in[20];
    const void* att2 = d_in[21]; const void* bo2 = d_in[22];
    const void* g1 = d_in[23]; const void* beta1 = d_in[24];
    const void* g2 = d_in[25]; const void* beta2 = d_in[26];
    const void* W_out = d_in[27]; const void* b_out = d_in[28];

    // workspace (~54 MB), 16B-aligned sections:
    int*   cnt  = (int*)d_ws;                              // 64 ints
    uint4* ea8  = (uint4*)((char*)d_ws + 256);             // NE uint4
    bf16*  zb   = (bf16*)(ea8 + NE);                       // NN*HIDD
    bf16*  xl   = zb + NN * HIDD;                          // NN*HIDD
    bf16*  xr   = xl + NN * HIDD;                          // NN*HIDD
    bf16*  wbT  = xr + NN * HIDD;                          // 2*256*128
    float* bias = (float*)(wbT + 2 * 256 * HIDD);          // 2*256
    int*   off  = (int*)(bias + 2 * 256);                  // NN+1
    int*   deg  = off + NN + 1;                            // NN
    int*   rank = deg + NN;                                // NE
    int*   esrc = rank + NE;                               // NE
    int*   bsum = esrc + NE;                               // 256

    int nhalf = in_sizes[0] < 65536 ? in_sizes[0] : 65536;
    k_init0<<<(NN + 255) / 256, 256, 0, stream>>>(cnt, deg);
    k_detect<<<64, 256, 0, stream>>>((const unsigned short*)x, nhalf, cnt);
    k_build_z<<<NN, 128, 0, stream>>>(cnt, x, node_idx, emb, W_in, b_in, zb);

    // CSR by dst (shared by both layers)
    k_hist<<<(NE + 255) / 256, 256, 0, stream>>>(ei, deg, rank);
    k_scan1<<<NB_SCAN, 256, 0, stream>>>(deg, off, bsum);
    k_scan2<<<1, 256, 0, stream>>>(bsum);
    k_scan3<<<NB_SCAN, 256, 0, stream>>>(off, bsum);
    k_fill<<<(NE + 255) / 256, 256, 0, stream>>>(cnt, ei, off, rank, esrc, ea8, ea);

    k_prepw<<<512, HIDD, 0, stream>>>(cnt, Wl1, bl1, Wr1, br1, Wl2, bl2, Wr2, br2, wbT, bias);

    // ---- layer 1 ----
    k_projmm<<<(NN + 63) / 64, 256, 0, stream>>>(zb, wbT, bias, xl, xr);
    k_gat<<<NN / 8, 256, 0, stream>>>(cnt, off, esrc, ea8, We1, be1, att1, xl, xr, bo1, zb, g1, beta1);

    // ---- layer 2 ----
    k_projmm<<<(NN + 63) / 64, 256, 0, stream>>>(zb, wbT + 256 * HIDD, bias + 256, xl, xr);
    k_gat_last<<<NN / 8, 256, 0, stream>>>(cnt, off, esrc, ea8, We2, be2, att2, xl, xr, bo2, zb,
                                           g2, beta2, W_out, b_out, d_out);
}

// Round 12
// 408.913 us; speedup vs baseline: 3.8940x; 1.0340x over previous
//
#include <hip/hip_runtime.h>
#include <hip/hip_bf16.h>

#define NN 50000
#define NE 600000
#define IND 16
#define EDD 8
#define HIDD 128
#define NH 4
#define CC 32
#define EMBD 64
#define FEATD 64
#define NB_SCAN ((NN + 255) / 256)  // 196

typedef __hip_bfloat16 bf16;
typedef __attribute__((ext_vector_type(8))) short bshort8;
typedef __attribute__((ext_vector_type(4))) float floatx4;

// round-to-nearest-even f32 -> bf16 bits
__device__ __forceinline__ unsigned short f2bu(float f) {
    unsigned int u = __float_as_uint(f);
    u += 0x7fffu + ((u >> 16) & 1u);
    return (unsigned short)(u >> 16);
}

template <bool F32>
__device__ __forceinline__ float LD(const void* p, long long i) {
    if constexpr (F32) return ((const float*)p)[i];
    else return __bfloat162float(((const bf16*)p)[i]);
}

// ---- zero cnt + deg + dcnt in one launch
__global__ void k_init0(int* __restrict__ cnt, int* __restrict__ deg, int* __restrict__ dcnt) {
    int i = blockIdx.x * blockDim.x + threadIdx.x;
    if (i == 0) *cnt = 0;
    if (i < NN) deg[i] = 0;
    if (i < 64) dcnt[i] = 0;
}

// ---- dtype detector (fp32 misread as bf16 shows ~2^-8 rate of exp==0xFF halfwords)
__global__ void k_detect(const unsigned short* __restrict__ x, int nhalf, int* __restrict__ cnt) {
    __shared__ int c;
    if (threadIdx.x == 0) c = 0;
    __syncthreads();
    int i = blockIdx.x * blockDim.x + threadIdx.x;
    int hits = 0;
    for (; i < nhalf; i += gridDim.x * blockDim.x)
        if ((x[i] & 0x7F80u) == 0x7F80u) hits++;
    if (hits) atomicAdd(&c, hits);
    __syncthreads();
    if (threadIdx.x == 0 && c) atomicAdd(cnt, c);
}

__device__ __forceinline__ bool is_f32(const int* cnt) { return *cnt > 8; }

// ---- CSR: histogram also records each edge's rank within its dst bucket
__global__ void k_hist(const int* __restrict__ ei, int* __restrict__ deg, int* __restrict__ rank) {
    int e = blockIdx.x * blockDim.x + threadIdx.x;
    if (e < NE) rank[e] = atomicAdd(&deg[ei[NE + e]], 1);
}

// level 1: per-tile exclusive scan + block totals + degree-bucket local histogram
__global__ void k_scan1(const int* __restrict__ deg, int* __restrict__ off,
                        int* __restrict__ bsum, int* __restrict__ dcnt,
                        int* __restrict__ rankd) {
    __shared__ int tile[256];
    __shared__ int lh[64];
    __shared__ int lbase[64];
    int t = threadIdx.x;
    int gid = blockIdx.x * 256 + t;
    if (t < 64) lh[t] = 0;
    __syncthreads();
    int v = (gid < NN) ? deg[gid] : 0;
    int b = min(v, 63);
    int lr = 0;
    if (gid < NN) lr = atomicAdd(&lh[b], 1);
    tile[t] = v;
    __syncthreads();
    if (t < 64) lbase[t] = lh[t] ? atomicAdd(&dcnt[t], lh[t]) : 0;
    #pragma unroll
    for (int o = 1; o < 256; o <<= 1) {
        int u = (t >= o) ? tile[t - o] : 0;
        __syncthreads();
        tile[t] += u;
        __syncthreads();
    }
    if (gid < NN) {
        off[gid] = tile[t] - v;
        rankd[gid] = lbase[b] + lr;
    }
    if (t == 255) bsum[blockIdx.x] = tile[255];
}
// level 2: scan block sums (196) and degree buckets (64), both exclusive
__global__ void k_scan2(int* __restrict__ bsum, int* __restrict__ dcnt,
                        int* __restrict__ dbase) {
    __shared__ int tile[256];
    __shared__ int d2[64];
    int t = threadIdx.x;
    int v = (t < NB_SCAN) ? bsum[t] : 0;
    tile[t] = v;
    int dv = (t < 64) ? dcnt[t] : 0;
    if (t < 64) d2[t] = dv;
    __syncthreads();
    #pragma unroll
    for (int o = 1; o < 256; o <<= 1) {
        int u = (t >= o) ? tile[t - o] : 0;
        __syncthreads();
        tile[t] += u;
        __syncthreads();
    }
    #pragma unroll
    for (int o = 1; o < 64; o <<= 1) {
        int u = (t >= o && t < 64) ? d2[t - o] : 0;
        __syncthreads();
        if (t < 64) d2[t] += u;
        __syncthreads();
    }
    if (t < NB_SCAN) bsum[t] = tile[t] - v;
    if (t < 64) dbase[t] = d2[t] - dv;
}
// level 3: finalize off; scatter degree-sorted node permutation
__global__ void k_scan3(int* __restrict__ off, const int* __restrict__ bsum,
                        const int* __restrict__ deg, const int* __restrict__ rankd,
                        const int* __restrict__ dbase, int* __restrict__ perm) {
    int gid = blockIdx.x * 256 + threadIdx.x;
    if (gid < NN) {
        off[gid] += bsum[blockIdx.x];
        int b = min(deg[gid], 63);
        perm[dbase[b] + rankd[gid]] = gid;
    }
    if (gid == 0) off[NN] = NE;
}

// slot = off[dst] + rank[e] -> esrc + packed bf16 edge_attr, CSR-sorted. No atomics.
// Thread 0 also writes the pad slot (index NE) used by unconditional prefetch.
template <bool F32>
__device__ void fill_impl(const int* __restrict__ ei, const int* __restrict__ off,
                          const int* __restrict__ rank, int* __restrict__ esrc,
                          uint4* __restrict__ ea8, const void* ea) {
    int e = blockIdx.x * blockDim.x + threadIdx.x;
    if (e >= NE) return;
    if (e == 0) {
        esrc[NE] = 0;
        uint4 z; z.x = 0; z.y = 0; z.z = 0; z.w = 0;
        ea8[NE] = z;
    }
    int slot = off[ei[NE + e]] + rank[e];
    esrc[slot] = ei[e];
    unsigned int w[4];
    #pragma unroll
    for (int d = 0; d < 4; d++) {
        unsigned int lo = f2bu(LD<F32>(ea, (long long)e * EDD + 2 * d));
        unsigned int hi = f2bu(LD<F32>(ea, (long long)e * EDD + 2 * d + 1));
        w[d] = lo | (hi << 16);
    }
    uint4 v; v.x = w[0]; v.y = w[1]; v.z = w[2]; v.w = w[3];
    ea8[slot] = v;
}
__global__ void k_fill(const int* cnt, const int* ei, const int* off, const int* rank,
                       int* esrc, uint4* ea8, const void* ea) {
    if (is_f32(cnt)) fill_impl<true>(ei, off, rank, esrc, ea8, ea);
    else             fill_impl<false>(ei, off, rank, esrc, ea8, ea);
}

// ---- merged: build_z (blocks 0..NN-1) + weight prep (blocks NN..NN+511)
template <bool F32>
__device__ void bzpw_impl(const void* x, const int* __restrict__ node_idx, const void* emb,
                          const void* W_in, const void* b_in, bf16* __restrict__ zb,
                          const void* Wl1, const void* bl1, const void* Wr1, const void* br1,
                          const void* Wl2, const void* bl2, const void* Wr2, const void* br2,
                          bf16* __restrict__ wbT, float* __restrict__ bias) {
    int t = threadIdx.x;  // 128
    if (blockIdx.x < NN) {
        int n = blockIdx.x;
        float val;
        if (t < FEATD) {
            float acc = LD<F32>(b_in, t);
            #pragma unroll
            for (int k = 0; k < IND; k++)
                acc += LD<F32>(x, (long long)n * IND + k) * LD<F32>(W_in, k * FEATD + t);
            val = fmaxf(acc, 0.f);
        } else {
            val = LD<F32>(emb, (long long)node_idx[n] * EMBD + (t - FEATD));
        }
        zb[n * HIDD + t] = __float2bfloat16(val);
    } else {
        int bid = blockIdx.x - NN;
        int layer = bid >> 8;
        int n = bid & 255;
        const void* W = layer ? (n < HIDD ? Wl2 : Wr2) : (n < HIDD ? Wl1 : Wr1);
        const void* b = layer ? (n < HIDD ? bl2 : br2) : (n < HIDD ? bl1 : br1);
        int nn = n & (HIDD - 1);
        wbT[(layer * 256 + n) * HIDD + t] = __float2bfloat16(LD<F32>(W, t * HIDD + nn));
        if (t == 0) bias[layer * 256 + n] = LD<F32>(b, nn);
    }
}
__global__ void k_bzpw(const int* cnt, const void* x, const int* node_idx, const void* emb,
                       const void* W_in, const void* b_in, bf16* zb,
                       const void* Wl1, const void* bl1, const void* Wr1, const void* br1,
                       const void* Wl2, const void* bl2, const void* Wr2, const void* br2,
                       bf16* wbT, float* bias) {
    if (is_f32(cnt)) bzpw_impl<true>(x, node_idx, emb, W_in, b_in, zb, Wl1, bl1, Wr1, br1,
                                     Wl2, bl2, Wr2, br2, wbT, bias);
    else             bzpw_impl<false>(x, node_idx, emb, W_in, b_in, zb, Wl1, bl1, Wr1, br1,
                                      Wl2, bl2, Wr2, br2, wbT, bias);
}

// ---- MFMA projection: [xl|xr] = zb @ wbT^T + bias. 32-row M-tile per block
// (1563 blocks => ~6/CU), both A-subtiles' loads issued before the MFMA chain.
__global__ __launch_bounds__(256) void k_projmm(const bf16* __restrict__ zb,
                                                const bf16* __restrict__ wbT,
                                                const float* __restrict__ bias,
                                                bf16* __restrict__ xl, bf16* __restrict__ xr) {
    int wave = threadIdx.x >> 6, lane = threadIdx.x & 63;
    int m0 = blockIdx.x * 32;
    int n0 = wave * 64;
    int l15 = lane & 15, q = lane >> 4;
    bshort8 bfr[4][4];  // [j][s]
    #pragma unroll
    for (int j = 0; j < 4; j++)
        #pragma unroll
        for (int s = 0; s < 4; s++)
            bfr[j][s] = *(const bshort8*)(wbT + ((n0 + j * 16 + l15) << 7) + s * 32 + q * 8);
    float bv[4];
    #pragma unroll
    for (int j = 0; j < 4; j++) bv[j] = bias[n0 + j * 16 + l15];
    // A loads for both 16-row subtiles (reads past row NN land in ws scratch; stores guarded)
    const bf16* arow0 = zb + ((m0 + l15) << 7) + q * 8;
    const bf16* arow1 = arow0 + (16 << 7);
    bshort8 a0[4], a1[4];
    #pragma unroll
    for (int s = 0; s < 4; s++) a0[s] = *(const bshort8*)(arow0 + s * 32);
    #pragma unroll
    for (int s = 0; s < 4; s++) a1[s] = *(const bshort8*)(arow1 + s * 32);
    #pragma unroll
    for (int mi = 0; mi < 2; mi++) {
        floatx4 acc0 = {0.f, 0.f, 0.f, 0.f}, acc1 = acc0, acc2 = acc0, acc3 = acc0;
        #pragma unroll
        for (int s = 0; s < 4; s++) {
            bshort8 a = mi ? a1[s] : a0[s];
            acc0 = __builtin_amdgcn_mfma_f32_16x16x32_bf16(a, bfr[0][s], acc0, 0, 0, 0);
            acc1 = __builtin_amdgcn_mfma_f32_16x16x32_bf16(a, bfr[1][s], acc1, 0, 0, 0);
            acc2 = __builtin_amdgcn_mfma_f32_16x16x32_bf16(a, bfr[2][s], acc2, 0, 0, 0);
            acc3 = __builtin_amdgcn_mfma_f32_16x16x32_bf16(a, bfr[3][s], acc3, 0, 0, 0);
        }
        floatx4 accs[4] = {acc0, acc1, acc2, acc3};
        #pragma unroll
        for (int j = 0; j < 4; j++) {
            int colg = n0 + j * 16 + l15;
            bf16* dst = (colg < HIDD) ? (xl + colg) : (xr + (colg - HIDD));
            #pragma unroll
            for (int r = 0; r < 4; r++) {
                int rowc = m0 + mi * 16 + q * 4 + r;
                if (rowc < NN) dst[rowc << 7] = __float2bfloat16(accs[j][r] + bv[j]);
            }
        }
    }
}

// ---- fused GAT layer: 2 nodes per wave (degree-matched via perm), 4 ch/lane,
// unconditional pad-backed prefetch, 32-bit addressing, barrier-free LN.
// LAST fuses the output head.
template <bool F32, bool LAST>
__device__ void gat_impl(const int* __restrict__ perm,
                         const int* __restrict__ off, const int* __restrict__ esrc,
                         const uint4* __restrict__ ea8,
                         const void* We, const void* be, const void* att,
                         const bf16* __restrict__ xl, const bf16* __restrict__ xr,
                         const void* bo, bf16* __restrict__ zb,
                         const void* g, const void* beta,
                         const void* Wo, const void* bout, void* out) {
    int wave = threadIdx.x >> 6;
    int half = (threadIdx.x >> 5) & 1;
    int lane5 = threadIdx.x & 31;
    int n = perm[blockIdx.x * 8 + wave * 2 + half];
    int c0 = lane5 << 2;  // 4 channels c0..c0+3 ; head = lane5>>3
    float wv[EDD][4], at[4], bev[4];
    #pragma unroll
    for (int d = 0; d < EDD; d++)
        #pragma unroll
        for (int j = 0; j < 4; j++) wv[d][j] = LD<F32>(We, d * HIDD + c0 + j);
    #pragma unroll
    for (int j = 0; j < 4; j++) {
        at[j] = LD<F32>(att, c0 + j);
        bev[j] = LD<F32>(be, c0 + j);
    }
    uint2 xru = *(const uint2*)(xr + (n << 7) + c0);
    float xrv[4];
    xrv[0] = __uint_as_float(xru.x << 16);
    xrv[1] = __uint_as_float(xru.x & 0xffff0000u);
    xrv[2] = __uint_as_float(xru.y << 16);
    xrv[3] = __uint_as_float(xru.y & 0xffff0000u);
    int lo = off[n], hi = off[n + 1];
    float acc[4] = {0.f, 0.f, 0.f, 0.f};
    float den = 0.f;
    if (lo < hi) {
        int src = esrc[lo];
        uint4 eu = ea8[lo];
        uint2 xu = *(const uint2*)(xl + (src << 7) + c0);
        for (int i = lo; i < hi; i++) {
            int src_n = esrc[i + 1];        // pad slot at NE keeps this in-bounds
            uint4 eu_n = ea8[i + 1];
            uint2 xu_n = *(const uint2*)(xl + (src_n << 7) + c0);
            float e[8];
            e[0] = __uint_as_float(eu.x << 16); e[1] = __uint_as_float(eu.x & 0xffff0000u);
            e[2] = __uint_as_float(eu.y << 16); e[3] = __uint_as_float(eu.y & 0xffff0000u);
            e[4] = __uint_as_float(eu.z << 16); e[5] = __uint_as_float(eu.z & 0xffff0000u);
            e[6] = __uint_as_float(eu.w << 16); e[7] = __uint_as_float(eu.w & 0xffff0000u);
            float xv[4];
            xv[0] = __uint_as_float(xu.x << 16);
            xv[1] = __uint_as_float(xu.x & 0xffff0000u);
            xv[2] = __uint_as_float(xu.y << 16);
            xv[3] = __uint_as_float(xu.y & 0xffff0000u);
            float ls = 0.f;
            #pragma unroll
            for (int j = 0; j < 4; j++) {
                float ee = bev[j];
                #pragma unroll
                for (int d = 0; d < EDD; d++) ee += e[d] * wv[d][j];
                float s = xv[j] + xrv[j] + ee;
                s = fmaxf(s, 0.2f * s);  // leakyrelu
                ls += s * at[j];
            }
            ls += __shfl_xor(ls, 1);
            ls += __shfl_xor(ls, 2);
            ls += __shfl_xor(ls, 4);   // 8-lane head group = 32 channels
            float ex = __expf(ls);
            #pragma unroll
            for (int j = 0; j < 4; j++) acc[j] += ex * xv[j];
            den += ex;
            src = src_n; eu = eu_n; xu = xu_n;
        }
    }
    float inv = (den > 0.f) ? 1.0f / den : 0.f;
    uint2 zu = *(const uint2*)(zb + (n << 7) + c0);
    float zv[4];
    zv[0] = __uint_as_float(zu.x << 16);
    zv[1] = __uint_as_float(zu.x & 0xffff0000u);
    zv[2] = __uint_as_float(zu.y << 16);
    zv[3] = __uint_as_float(zu.y & 0xffff0000u);
    float v[4];
    float s = 0.f;
    #pragma unroll
    for (int j = 0; j < 4; j++) {
        float hv = fmaxf(acc[j] * inv + LD<F32>(bo, c0 + j), 0.f);
        v[j] = zv[j] + hv;
        s += v[j];
    }
    #pragma unroll
    for (int m = 16; m; m >>= 1) s += __shfl_xor(s, m);  // 32-lane sum
    float mu = s * (1.f / HIDD);
    float s2 = 0.f;
    float dv[4];
    #pragma unroll
    for (int j = 0; j < 4; j++) { dv[j] = v[j] - mu; s2 += dv[j] * dv[j]; }
    #pragma unroll
    for (int m = 16; m; m >>= 1) s2 += __shfl_xor(s2, m);
    float rs = rsqrtf(s2 * (1.f / HIDD) + 1e-5f);
    float o[4];
    #pragma unroll
    for (int j = 0; j < 4; j++)
        o[j] = dv[j] * rs * LD<F32>(g, c0 + j) + LD<F32>(beta, c0 + j);
    if constexpr (!LAST) {
        uint2 pk;
        pk.x = (unsigned int)f2bu(o[0]) | ((unsigned int)f2bu(o[1]) << 16);
        pk.y = (unsigned int)f2bu(o[2]) | ((unsigned int)f2bu(o[3]) << 16);
        *(uint2*)(zb + (n << 7) + c0) = pk;
    } else {
        float po = 0.f;
        #pragma unroll
        for (int j = 0; j < 4; j++) po += o[j] * LD<F32>(Wo, c0 + j);
        #pragma unroll
        for (int m = 16; m; m >>= 1) po += __shfl_xor(po, m);
        if (lane5 == 0) {
            float r = po + LD<F32>(bout, 0);
            if constexpr (F32) ((float*)out)[n] = r;
            else               ((bf16*)out)[n] = __float2bfloat16(r);
        }
    }
}
__global__ void k_gat(const int* cnt, const int* perm, const int* off, const int* esrc,
                      const uint4* ea8, const void* We, const void* be, const void* att,
                      const bf16* xl, const bf16* xr, const void* bo, bf16* zb,
                      const void* g, const void* beta) {
    if (is_f32(cnt)) gat_impl<true, false>(perm, off, esrc, ea8, We, be, att, xl, xr, bo, zb, g, beta, nullptr, nullptr, nullptr);
    else             gat_impl<false, false>(perm, off, esrc, ea8, We, be, att, xl, xr, bo, zb, g, beta, nullptr, nullptr, nullptr);
}
__global__ void k_gat_last(const int* cnt, const int* perm, const int* off, const int* esrc,
                           const uint4* ea8, const void* We, const void* be, const void* att,
                           const bf16* xl, const bf16* xr, const void* bo, bf16* zb,
                           const void* g, const void* beta,
                           const void* Wo, const void* bout, void* out) {
    if (is_f32(cnt)) gat_impl<true, true>(perm, off, esrc, ea8, We, be, att, xl, xr, bo, zb, g, beta, Wo, bout, out);
    else             gat_impl<false, true>(perm, off, esrc, ea8, We, be, att, xl, xr, bo, zb, g, beta, Wo, bout, out);
}

extern "C" void kernel_launch(void* const* d_in, const int* in_sizes, int n_in,
                              void* d_out, int out_size, void* d_ws, size_t ws_size,
                              hipStream_t stream) {
    const void* x        = d_in[0];
    const int*  node_idx = (const int*)d_in[1];
    const int*  ei       = (const int*)d_in[2];
    const void* ea       = d_in[3];
    const void* emb      = d_in[4];
    const void* W_in     = d_in[5];
    const void* b_in     = d_in[6];
    const void* Wl1 = d_in[7];  const void* bl1 = d_in[8];
    const void* Wr1 = d_in[9];  const void* br1 = d_in[10];
    const void* We1 = d_in[11]; const void* be1 = d_in[12];
    const void* att1 = d_in[13]; const void* bo1 = d_in[14];
    const void* Wl2 = d_in[15]; const void* bl2 = d_in[16];
    const void* Wr2 = d_in[17]; const void* br2 = d_in[18];
    const void* We2 = d_in[19]; const void* be2 = d_in[20];
    const void* att2 = d_in[21]; const void* bo2 = d_in[22];
    const void* g1 = d_in[23]; const void* beta1 = d_in[24];
    const void* g2 = d_in[25]; const void* beta2 = d_in[26];
    const void* W_out = d_in[27]; const void* b_out = d_in[28];

    // workspace (~54 MB), 16B-aligned sections:
    int*   cnt   = (int*)d_ws;                             // 64 ints
    uint4* ea8   = (uint4*)((char*)d_ws + 256);            // NE+4 (pad slot at NE)
    bf16*  zb    = (bf16*)(ea8 + NE + 4);                  // NN*HIDD
    bf16*  xl    = zb + NN * HIDD;                         // NN*HIDD
    bf16*  xr    = xl + NN * HIDD;                         // NN*HIDD
    bf16*  wbT   = xr + NN * HIDD;                         // 2*256*128
    float* bias  = (float*)(wbT + 2 * 256 * HIDD);         // 512
    int*   off   = (int*)(bias + 512);                     // NN+1
    int*   deg   = off + NN + 1;                           // NN
    int*   rank  = deg + NN;                               // NE
    int*   rankd = rank + NE;                              // NN
    int*   perm  = rankd + NN;                             // NN
    int*   esrc  = perm + NN;                              // NE+4 (pad at NE)
    int*   bsum  = esrc + NE + 4;                          // 256
    int*   dcnt  = bsum + 256;                             // 64
    int*   dbase = dcnt + 64;                              // 64

    int nhalf = in_sizes[0] < 65536 ? in_sizes[0] : 65536;
    k_init0<<<(NN + 255) / 256, 256, 0, stream>>>(cnt, deg, dcnt);
    k_detect<<<64, 256, 0, stream>>>((const unsigned short*)x, nhalf, cnt);
    k_bzpw<<<NN + 512, HIDD, 0, stream>>>(cnt, x, node_idx, emb, W_in, b_in, zb,
                                          Wl1, bl1, Wr1, br1, Wl2, bl2, Wr2, br2, wbT, bias);

    // CSR by dst + degree-sorted node permutation (shared by both layers)
    k_hist<<<(NE + 255) / 256, 256, 0, stream>>>(ei, deg, rank);
    k_scan1<<<NB_SCAN, 256, 0, stream>>>(deg, off, bsum, dcnt, rankd);
    k_scan2<<<1, 256, 0, stream>>>(bsum, dcnt, dbase);
    k_scan3<<<NB_SCAN, 256, 0, stream>>>(off, bsum, deg, rankd, dbase, perm);
    k_fill<<<(NE + 255) / 256, 256, 0, stream>>>(cnt, ei, off, rank, esrc, ea8, ea);

    // ---- layer 1 ----
    k_projmm<<<(NN + 31) / 32, 256, 0, stream>>>(zb, wbT, bias, xl, xr);
    k_gat<<<NN / 8, 256, 0, stream>>>(cnt, perm, off, esrc, ea8, We1, be1, att1, xl, xr, bo1, zb, g1, beta1);

    // ---- layer 2 ----
    k_projmm<<<(NN + 31) / 32, 256, 0, stream>>>(zb, wbT + 256 * HIDD, bias + 256, xl, xr);
    k_gat_last<<<NN / 8, 256, 0, stream>>>(cnt, perm, off, esrc, ea8, We2, be2, att2, xl, xr, bo2, zb,
                                           g2, beta2, W_out, b_out, d_out);
}